// Round 2
// baseline (894.209 us; speedup 1.0000x reference)
//
#include <hip/hip_runtime.h>

typedef unsigned short u16;
typedef unsigned int u32;
typedef __attribute__((ext_vector_type(4))) float f32x4;
typedef __attribute__((ext_vector_type(4))) u16 u16x4;
typedef __attribute__((ext_vector_type(8))) u16 u16x8;
typedef __attribute__((ext_vector_type(8))) __bf16 bf16x8;

#define FLA_EPS 1e-6f

__device__ __forceinline__ u16 f2b(float f) {
  union { float f; u32 u; } v; v.f = f;
  u32 r = v.u + 0x7FFFu + ((v.u >> 16) & 1u);
  return (u16)(r >> 16);
}
__device__ __forceinline__ float b2f(u16 h) {
  union { u32 u; float f; } v; v.u = ((u32)h) << 16; return v.f;
}
__device__ __forceinline__ void g2l16(const void* g, void* l) {
  __builtin_amdgcn_global_load_lds((__attribute__((address_space(1))) void*)g,
                                   (__attribute__((address_space(3))) void*)l,
                                   16, 0, 0);
}

// ---------------- cast x fp32 -> bf16 ----------------
__global__ void __launch_bounds__(256) cast_f32_bf16(const float* __restrict__ in,
                                                     u16* __restrict__ out) {
  size_t i = (size_t)blockIdx.x * 256 + threadIdx.x;
  const f32x4* p = (const f32x4*)in + i * 2;
  f32x4 a = p[0], b = p[1];
  u16x8 r;
  r[0] = f2b(a[0]); r[1] = f2b(a[1]); r[2] = f2b(a[2]); r[3] = f2b(a[3]);
  r[4] = f2b(b[0]); r[5] = f2b(b[1]); r[6] = f2b(b[2]); r[7] = f2b(b[3]);
  ((u16x8*)out)[i] = r;
}

// ---------------- transpose + cast: Wt[n][k] = bf16(W[k][n]) ----------------
__global__ void __launch_bounds__(256) transpose_cast(const float* __restrict__ W,
                                                      u16* __restrict__ Wt, int dim) {
  __shared__ float tile[64][65];
  const int t = threadIdx.x;
  const int k0 = blockIdx.x * 64, n0 = blockIdx.y * 64;
  const int r = t >> 4, c4 = (t & 15) * 4;
#pragma unroll
  for (int i = 0; i < 4; ++i) {
    f32x4 vv = *(const f32x4*)(W + (size_t)(k0 + r + i * 16) * dim + n0 + c4);
    tile[r + i * 16][c4 + 0] = vv[0];
    tile[r + i * 16][c4 + 1] = vv[1];
    tile[r + i * 16][c4 + 2] = vv[2];
    tile[r + i * 16][c4 + 3] = vv[3];
  }
  __syncthreads();
#pragma unroll
  for (int i = 0; i < 4; ++i) {
    int nrow = r + i * 16;
    u16x4 o;
#pragma unroll
    for (int j = 0; j < 4; ++j) o[j] = f2b(tile[c4 + j][nrow]);
    *(u16x4*)(Wt + (size_t)(n0 + nrow) * dim + k0 + c4) = o;
  }
}

// ---------------- fold proj into Wq/Wk ----------------
__global__ void __launch_bounds__(256) fold_w(const float* __restrict__ Wq,
                                              const float* __restrict__ Wk,
                                              const float* __restrict__ proj,
                                              u16* __restrict__ WqkvT) {
  __shared__ float Wt[64][65];
  __shared__ float P[64][64];
  const int t = threadIdx.x;
  const int kbase = blockIdx.x * 64, h = blockIdx.y, sel = blockIdx.z;
  const float* W = sel ? Wk : Wq;
  {
    int row = t >> 2, cb = (t & 3) * 16;
#pragma unroll
    for (int i = 0; i < 4; ++i) {
      f32x4 vv = *(const f32x4*)(W + (size_t)(kbase + row) * 1024 + h * 64 + cb + i * 4);
      Wt[row][cb + i * 4 + 0] = vv[0]; Wt[row][cb + i * 4 + 1] = vv[1];
      Wt[row][cb + i * 4 + 2] = vv[2]; Wt[row][cb + i * 4 + 3] = vv[3];
      f32x4 pp = *(const f32x4*)(proj + (size_t)row * 64 + cb + i * 4);
      P[row][cb + i * 4 + 0] = pp[0]; P[row][cb + i * 4 + 1] = pp[1];
      P[row][cb + i * 4 + 2] = pp[2]; P[row][cb + i * 4 + 3] = pp[3];
    }
  }
  __syncthreads();
  const int kk = t & 63, fg = (t >> 6) * 16;
  float acc[16] = {};
  for (int d = 0; d < 64; ++d) {
    float w = Wt[kk][d];
#pragma unroll
    for (int ff = 0; ff < 16; ++ff) acc[ff] = fmaf(w, P[d][fg + ff], acc[ff]);
  }
#pragma unroll
  for (int ff = 0; ff < 16; ++ff)
    WqkvT[(size_t)(sel * 1024 + h * 64 + fg + ff) * 1024 + kbase + kk] = f2b(acc[ff]);
}

// ---------------- 256x256 BK=64 counted-lgkm deep-pipeline bf16 MFMA GEMM ----------------
// 512 thr = 8 waves (2M x 4N); per-wave C = 128x64 (8x4 frags of 16x16x32).
// vs round-1 8-phase: 2 barriers/tile (not 16), all ds_reads issued >=1 MFMA-cluster
// ahead, gated by counted lgkmcnt(8). Reads for tile t+1 (B panel + A half0) are
// issued at tile t's midpoint AFTER vmcnt(0)+s_barrier proves the staged buffer
// chip-wide valid; A half1 (af1) issued at tile head. Register lifetimes: af0/af1
// single sets (dead before their re-def), bf double set (live across midpoint).
// Stage discipline: A_{t+1} issued at head-t (into vacated A buf: WAR proven by
// end-barrier(t-1)); B_{t+2} issued after mid-barrier-t (B_R reads chip-wide done).
// vmcnt(0) at mid drains [B_{t+1}, A_{t+1}] only -- both >=1 cluster old, ~free.
template <int NB, bool QKV>
__global__ void __launch_bounds__(512, 2) gemm256(const u16* __restrict__ Ax,
                                                  const u16* __restrict__ Bt,
                                                  u16* __restrict__ qo, u16* __restrict__ ko,
                                                  u16* __restrict__ vo,
                                                  float* __restrict__ Cf,
                                                  const float* __restrict__ bias) {
  extern __shared__ __align__(16) u16 lds[];
  const int tid = threadIdx.x;
  // XCD swizzle: flat&7 = xcd; per XCD 16 m-blocks as 2 chunks of 8; n-major groups.
  const int flat = blockIdx.x;
  const int xcd = flat & 7, slot = flat >> 3;
  const int pos = slot & 7, g = slot >> 3;
  const int nc = g % NB, mc = g / NB;
  const int m0 = (xcd * 16 + mc * 8 + pos) * 256;
  const int n0 = nc * 256;
  const int w = tid >> 6, l = tid & 63, quad = l >> 4, lr = l & 15;
  const int wm = w >> 2, wn = w & 3;
  u16* const A0 = lds;                // buf0 A (2 halves of 8192 u16)
  u16* const B0 = lds + 16384;        // buf0 B
  u16* const A1 = lds + 32768;        // buf1 A
  u16* const B1 = lds + 49152;        // buf1 B
  // per-thread constant swizzled k-columns (u16 units) for the two ks slots
  const int c0 = ((quad * 16) ^ ((lr & 7) << 4)) >> 1;
  const int c1 = ((64 + quad * 16) ^ ((lr & 7) << 4)) >> 1;
  // staging: thread covers row rst (+64 for 2nd load), source col pre-swizzled
  const int rst = tid >> 3;
  const int ksw8 = ((tid & 7) ^ (rst & 7)) * 8;
  const int tid8 = tid * 8;

  f32x4 acc[8][4] = {};
  bf16x8 af0[4][2], af1[4][2], bfA[4][2], bfB[4][2];

#define STG(SRC, ROW0, KT, DST) do {                                         \
    const u16* s_ = (SRC) + (size_t)((ROW0) + rst) * 1024 + (KT) + ksw8;     \
    g2l16(s_, (DST) + tid8);                                                 \
    g2l16(s_ + 64 * 1024, (DST) + 4096 + tid8);                              \
  } while (0)

#define RD_A(DSTA, BASE, MH) do {                                            \
    const u16* ap_ = (BASE) + wm * 8192 + (MH) * 4096;                       \
    _Pragma("unroll")                                                        \
    for (int ii = 0; ii < 4; ++ii) {                                         \
      const int ro_ = (ii * 16 + lr) * 64;                                   \
      DSTA[ii][0] = *(const bf16x8*)(ap_ + ro_ + c0);                        \
      DSTA[ii][1] = *(const bf16x8*)(ap_ + ro_ + c1);                        \
    } } while (0)

#define RD_B(DSTB, BASE) do {                                                \
    const u16* bp_ = (BASE) + (wn >> 1) * 8192 + (wn & 1) * 4096;            \
    _Pragma("unroll")                                                        \
    for (int jj = 0; jj < 4; ++jj) {                                         \
      const int ro_ = (jj * 16 + lr) * 64;                                   \
      DSTB[jj][0] = *(const bf16x8*)(bp_ + ro_ + c0);                        \
      DSTB[jj][1] = *(const bf16x8*)(bp_ + ro_ + c1);                        \
    } } while (0)

#define CLUSTER(AF, MH, BFS, NH) do {                                        \
    __builtin_amdgcn_s_setprio(1);                                           \
    _Pragma("unroll")                                                        \
    for (int ii = 0; ii < 4; ++ii)                                           \
      _Pragma("unroll")                                                      \
      for (int jj = 0; jj < 2; ++jj)                                         \
        _Pragma("unroll")                                                    \
        for (int ks = 0; ks < 2; ++ks)                                       \
          acc[(MH) * 4 + ii][(NH) * 2 + jj] =                                \
              __builtin_amdgcn_mfma_f32_16x16x32_bf16(                       \
                  AF[ii][ks], BFS[(NH) * 2 + jj][ks],                        \
                  acc[(MH) * 4 + ii][(NH) * 2 + jj], 0, 0, 0);               \
    __builtin_amdgcn_s_setprio(0);                                           \
  } while (0)

#define WAIT_LGKM8() do { asm volatile("s_waitcnt lgkmcnt(8)" ::: "memory"); \
    __builtin_amdgcn_sched_barrier(0); } while (0)
#define WAIT_LGKM0() do { asm volatile("s_waitcnt lgkmcnt(0)" ::: "memory"); \
    __builtin_amdgcn_sched_barrier(0); } while (0)
#define WAIT_VM0()  do { asm volatile("s_waitcnt vmcnt(0)" ::: "memory");    \
    __builtin_amdgcn_sched_barrier(0); } while (0)
#define BARRIER()   do { asm volatile("s_barrier" ::: "memory"); } while (0)

  // Per-tile body. Queue invariants (lgkm, in-order DS completion):
  //  head entry: [BFC(8), af0(8)] issued at prev mid; issue af1(8); WAIT(8) -> BFC+af0 done.
  //  mid: issue RD_B->BFN(8); WAIT(8) -> af1 done (C3/C4 operands); af0-next issued
  //  between C3/C4 drains under the clusters.
#define TILE(TV, ABUF, BBUF, ABUFN, BBUFN, BFC, BFN) do {                    \
    const int t_ = (TV);                                                     \
    if (t_ > 0 && t_ < 15) {                                                 \
      STG(Ax, m0, (t_ + 1) * 64, ABUFN);                                     \
      STG(Ax, m0 + 128, (t_ + 1) * 64, (ABUFN) + 8192);                      \
    }                                                                        \
    RD_A(af1, ABUF, 1);                                                      \
    WAIT_LGKM8();                                                            \
    CLUSTER(af0, 0, BFC, 0);                                                 \
    CLUSTER(af0, 0, BFC, 1);                                                 \
    if (t_ < 15) {                                                           \
      WAIT_VM0();                                                            \
      BARRIER();                                                             \
      if (t_ < 14) {                                                         \
        STG(Bt, n0, (t_ + 2) * 64, BBUF);                                    \
        STG(Bt, n0 + 128, (t_ + 2) * 64, (BBUF) + 8192);                     \
      }                                                                      \
      RD_B(BFN, BBUFN);                                                      \
      WAIT_LGKM8();                                                          \
    } else {                                                                 \
      WAIT_LGKM0();                                                          \
    }                                                                        \
    CLUSTER(af1, 1, BFC, 0);                                                 \
    if (t_ < 15) RD_A(af0, ABUFN, 0);                                        \
    CLUSTER(af1, 1, BFC, 1);                                                 \
    if (t_ < 15) BARRIER();                                                  \
  } while (0)

  // prologue: stage tiles 0 and 1; prove tile 0 resident; issue tile-0 early reads
  STG(Ax, m0, 0, A0); STG(Ax, m0 + 128, 0, A0 + 8192);
  STG(Bt, n0, 0, B0); STG(Bt, n0 + 128, 0, B0 + 8192);
  STG(Ax, m0, 64, A1); STG(Ax, m0 + 128, 64, A1 + 8192);
  STG(Bt, n0, 64, B1); STG(Bt, n0 + 128, 64, B1 + 8192);
  asm volatile("s_waitcnt vmcnt(8)" ::: "memory");
  __builtin_amdgcn_sched_barrier(0);
  BARRIER();
  RD_B(bfA, B0);
  RD_A(af0, A0, 0);

  for (int it = 0; it < 8; ++it) {
    TILE(2 * it,     A0, B0, A1, B1, bfA, bfB);
    TILE(2 * it + 1, A1, B1, A0, B0, bfB, bfA);
  }
#undef TILE
#undef STG
#undef RD_A
#undef RD_B
#undef CLUSTER
#undef WAIT_LGKM8
#undef WAIT_LGKM0
#undef WAIT_VM0
#undef BARRIER

  const int rbase = m0 + wm * 128 + quad * 4;
  if (QKV) {
    const int sel = n0 >> 10;
    u16* dst = (sel == 0) ? qo : ((sel == 1) ? ko : vo);
    const int cb = (n0 & 1023) + wn * 64 + lr;
#pragma unroll
    for (int mi = 0; mi < 8; ++mi)
#pragma unroll
      for (int nj = 0; nj < 4; ++nj)
#pragma unroll
        for (int rr = 0; rr < 4; ++rr) {
          int row = rbase + mi * 16 + rr;
          float v = acc[mi][nj][rr];
          if (sel < 2) v = fmaxf(v, 0.0f) + FLA_EPS;
          dst[(size_t)row * 1024 + cb + nj * 16] = f2b(v);
        }
  } else {
    const int cb = n0 + wn * 64 + lr;
#pragma unroll
    for (int mi = 0; mi < 8; ++mi)
#pragma unroll
      for (int nj = 0; nj < 4; ++nj)
#pragma unroll
        for (int rr = 0; rr < 4; ++rr) {
          int row = rbase + mi * 16 + rr;
          Cf[(size_t)row * 1024 + cb + nj * 16] = acc[mi][nj][rr] + bias[cb + nj * 16];
        }
  }
}

// ---------------- kv partials ----------------
__global__ void __launch_bounds__(256) kv_partial(const u16* __restrict__ kf,
                                                  const u16* __restrict__ v,
                                                  float* __restrict__ part,
                                                  float* __restrict__ ksum_p) {
  const int t = threadIdx.x;
  const int bh = blockIdx.x, b = bh >> 4, h = bh & 15;
  const int w = t >> 6, l = t & 63;
  const int sub = blockIdx.y * 4 + w;
  const int f0 = (l >> 3) * 8, d0 = (l & 7) * 8;
  const size_t rowbase = ((size_t)b * 8192 + (size_t)sub * 256) * 1024 + h * 64;
  float acc[8][8] = {};
  float ks[8] = {};
#pragma unroll 2
  for (int n = 0; n < 256; ++n) {
    u16x8 ka = *(const u16x8*)(kf + rowbase + (size_t)n * 1024 + f0);
    u16x8 va = *(const u16x8*)(v + rowbase + (size_t)n * 1024 + d0);
    float kff[8], vf[8];
#pragma unroll
    for (int i = 0; i < 8; ++i) { kff[i] = b2f(ka[i]); vf[i] = b2f(va[i]); }
#pragma unroll
    for (int i = 0; i < 8; ++i) {
      ks[i] += kff[i];
#pragma unroll
      for (int j = 0; j < 8; ++j) acc[i][j] = fmaf(kff[i], vf[j], acc[i][j]);
    }
  }
  float* pb = part + ((size_t)bh * 32 + sub) * 4096;
#pragma unroll
  for (int j = 0; j < 8; ++j)
#pragma unroll
    for (int i = 0; i < 8; i += 4) {
      f32x4 vv = { acc[i][j], acc[i + 1][j], acc[i + 2][j], acc[i + 3][j] };
      *(f32x4*)(pb + (d0 + j) * 64 + f0 + i) = vv;
    }
  if (d0 == 0) {
    float* kp = ksum_p + ((size_t)bh * 32 + sub) * 64 + f0;
    f32x4 a = { ks[0], ks[1], ks[2], ks[3] }, bq = { ks[4], ks[5], ks[6], ks[7] };
    *(f32x4*)(kp) = a; *(f32x4*)(kp + 4) = bq;
  }
}

__global__ void __launch_bounds__(256) reduce_kv(const float* __restrict__ part,
                                                 float* __restrict__ kvT) {
  int i = blockIdx.x * 256 + threadIdx.x;
  int bh = i >> 12, dfi = i & 4095;
  const float* p = part + (size_t)bh * 32 * 4096 + dfi;
  float s = 0.f;
#pragma unroll
  for (int sub = 0; sub < 32; ++sub) s += p[(size_t)sub * 4096];
  kvT[i] = s;
}

// ---------------- num/den + normalize ----------------
__global__ void __launch_bounds__(256) num_den(const u16* __restrict__ qf,
                                               const float* __restrict__ kvT,
                                               const float* __restrict__ ksum_p,
                                               u16* __restrict__ outI) {
  __shared__ __align__(16) u16 As[128 * 64];
  __shared__ __align__(16) u16 Bs[64 * 64];
  __shared__ float ksum_s[64];
  __shared__ float den_s[128];
  const int t = threadIdx.x;
  const size_t tok0 = (size_t)blockIdx.x * 128;
  const int h = blockIdx.y;
  const int bh = (blockIdx.x >> 6) * 16 + h;
  const int w = t >> 6, l = t & 63, quad = l >> 4, lr = l & 15;
  const int trow = t >> 3, tcol = (t & 7) * 8;
#pragma unroll
  for (int i = 0; i < 4; ++i) {
    int r = i * 32 + trow;
    g2l16(qf + (tok0 + r) * 1024 + h * 64 + tcol, &As[r * 64 + tcol]);
  }
  {
    const float* kvb = kvT + (size_t)bh * 4096;
    int d = t >> 2, cb = (t & 3) * 16;
    u16x8 o0, o1;
#pragma unroll
    for (int q4 = 0; q4 < 2; ++q4) {
      f32x4 vv = *(const f32x4*)(kvb + d * 64 + cb + q4 * 4);
      o0[q4 * 4 + 0] = f2b(vv[0]); o0[q4 * 4 + 1] = f2b(vv[1]);
      o0[q4 * 4 + 2] = f2b(vv[2]); o0[q4 * 4 + 3] = f2b(vv[3]);
    }
#pragma unroll
    for (int q4 = 0; q4 < 2; ++q4) {
      f32x4 vv = *(const f32x4*)(kvb + d * 64 + cb + 8 + q4 * 4);
      o1[q4 * 4 + 0] = f2b(vv[0]); o1[q4 * 4 + 1] = f2b(vv[1]);
      o1[q4 * 4 + 2] = f2b(vv[2]); o1[q4 * 4 + 3] = f2b(vv[3]);
    }
    *(u16x8*)&Bs[d * 64 + cb] = o0;
    *(u16x8*)&Bs[d * 64 + cb + 8] = o1;
  }
  if (t < 64) {
    float s = 0.f;
    const float* kp = ksum_p + (size_t)bh * 32 * 64 + t;
#pragma unroll
    for (int sub = 0; sub < 32; ++sub) s += kp[(size_t)sub * 64];
    ksum_s[t] = s;
  }
  __syncthreads();
  if (t < 128) {
    float d = FLA_EPS;
#pragma unroll
    for (int jj = 0; jj < 64; ++jj) {
      int f = (t + jj) & 63;
      d += b2f(As[t * 64 + f]) * ksum_s[f];
    }
    den_s[t] = d;
  }
  __syncthreads();
  f32x4 acc[2][4] = {};
  const int wrow = w * 32;
#pragma unroll
  for (int ks = 0; ks < 2; ++ks) {
    bf16x8 af[2], bfr[4];
#pragma unroll
    for (int i = 0; i < 2; ++i)
      af[i] = *(const bf16x8*)&As[(wrow + i * 16 + lr) * 64 + ks * 32 + quad * 8];
#pragma unroll
    for (int j = 0; j < 4; ++j)
      bfr[j] = *(const bf16x8*)&Bs[(j * 16 + lr) * 64 + ks * 32 + quad * 8];
#pragma unroll
    for (int i = 0; i < 2; ++i)
#pragma unroll
      for (int j = 0; j < 4; ++j)
        acc[i][j] = __builtin_amdgcn_mfma_f32_16x16x32_bf16(af[i], bfr[j], acc[i][j], 0, 0, 0);
  }
#pragma unroll
  for (int i = 0; i < 2; ++i)
#pragma unroll
    for (int j = 0; j < 4; ++j)
#pragma unroll
      for (int rr = 0; rr < 4; ++rr) {
        int rloc = wrow + i * 16 + quad * 4 + rr;
        float v = acc[i][j][rr] / den_s[rloc];
        outI[(tok0 + rloc) * 1024 + h * 64 + j * 16 + lr] = f2b(v);
      }
}

extern "C" void kernel_launch(void* const* d_in, const int* in_sizes, int n_in,
                              void* d_out, int out_size, void* d_ws, size_t ws_size,
                              hipStream_t stream) {
  const float* x    = (const float*)d_in[0];
  const float* Wq   = (const float*)d_in[1];
  const float* Wk   = (const float*)d_in[2];
  const float* Wv   = (const float*)d_in[3];
  const float* proj = (const float*)d_in[4];
  const float* Wo   = (const float*)d_in[5];
  const float* bo   = (const float*)d_in[6];
  float* out = (float*)d_out;

  char* ws = (char*)d_ws;
  const size_t SZ = 1ull << 26;
  u16* xb     = (u16*)(ws + 0);
  u16* qb     = (u16*)(ws + SZ);
  u16* kb     = (u16*)(ws + 2 * SZ);
  u16* vb     = (u16*)(ws + 3 * SZ);
  u16* WqkvT  = (u16*)(ws + 4 * SZ);
  u16* woT    = (u16*)(ws + 4 * SZ + 0x600000);
  float* part   = (float*)(ws + 4 * SZ + 0x800000);
  float* ksum_p = (float*)(ws + 4 * SZ + 0x800000 + 0x2000000);
  float* kvT    = (float*)(ws + 4 * SZ + 0x800000 + 0x2080000);

  static int attr_done = 0;
  if (!attr_done) {
    (void)hipFuncSetAttribute((const void*)gemm256<12, true>,
                              hipFuncAttributeMaxDynamicSharedMemorySize, 131072);
    (void)hipFuncSetAttribute((const void*)gemm256<4, false>,
                              hipFuncAttributeMaxDynamicSharedMemorySize, 131072);
    attr_done = 1;
  }

  cast_f32_bf16<<<16384, 256, 0, stream>>>(x, xb);
  fold_w<<<dim3(16, 16, 2), 256, 0, stream>>>(Wq, Wk, proj, WqkvT);
  transpose_cast<<<dim3(16, 16), 256, 0, stream>>>(Wv, WqkvT + (size_t)2048 * 1024, 1024);
  transpose_cast<<<dim3(16, 16), 256, 0, stream>>>(Wo, woT, 1024);
  gemm256<12, true><<<1536, 512, 131072, stream>>>(xb, WqkvT, qb, kb, vb, nullptr, nullptr);
  kv_partial<<<dim3(64, 8), 256, 0, stream>>>(kb, vb, part, ksum_p);
  reduce_kv<<<1024, 256, 0, stream>>>(part, kvT);
  num_den<<<dim3(256, 16), 256, 0, stream>>>(qb, kvT, ksum_p, xb);
  gemm256<4, false><<<512, 512, 131072, stream>>>(xb, woT, nullptr, nullptr, nullptr, out, bo);
}

// Round 3
// 655.075 us; speedup vs baseline: 1.3650x; 1.3650x over previous
//
#include <hip/hip_runtime.h>

typedef unsigned short u16;
typedef unsigned int u32;
typedef __attribute__((ext_vector_type(4))) float f32x4;
typedef __attribute__((ext_vector_type(4))) u16 u16x4;
typedef __attribute__((ext_vector_type(8))) u16 u16x8;
typedef __attribute__((ext_vector_type(8))) __bf16 bf16x8;

#define FLA_EPS 1e-6f

__device__ __forceinline__ u16 f2b(float f) {
  union { float f; u32 u; } v; v.f = f;
  u32 r = v.u + 0x7FFFu + ((v.u >> 16) & 1u);
  return (u16)(r >> 16);
}
__device__ __forceinline__ float b2f(u16 h) {
  union { u32 u; float f; } v; v.u = ((u32)h) << 16; return v.f;
}
__device__ __forceinline__ void g2l16(const void* g, void* l) {
  __builtin_amdgcn_global_load_lds((__attribute__((address_space(1))) void*)g,
                                   (__attribute__((address_space(3))) void*)l,
                                   16, 0, 0);
}

// ---------------- cast x fp32 -> bf16 ----------------
__global__ void __launch_bounds__(256) cast_f32_bf16(const float* __restrict__ in,
                                                     u16* __restrict__ out) {
  size_t i = (size_t)blockIdx.x * 256 + threadIdx.x;
  const f32x4* p = (const f32x4*)in + i * 2;
  f32x4 a = p[0], b = p[1];
  u16x8 r;
  r[0] = f2b(a[0]); r[1] = f2b(a[1]); r[2] = f2b(a[2]); r[3] = f2b(a[3]);
  r[4] = f2b(b[0]); r[5] = f2b(b[1]); r[6] = f2b(b[2]); r[7] = f2b(b[3]);
  ((u16x8*)out)[i] = r;
}

// ---------------- transpose + cast: Wt[n][k] = bf16(W[k][n]) ----------------
__global__ void __launch_bounds__(256) transpose_cast(const float* __restrict__ W,
                                                      u16* __restrict__ Wt, int dim) {
  __shared__ float tile[64][65];
  const int t = threadIdx.x;
  const int k0 = blockIdx.x * 64, n0 = blockIdx.y * 64;
  const int r = t >> 4, c4 = (t & 15) * 4;
#pragma unroll
  for (int i = 0; i < 4; ++i) {
    f32x4 vv = *(const f32x4*)(W + (size_t)(k0 + r + i * 16) * dim + n0 + c4);
    tile[r + i * 16][c4 + 0] = vv[0];
    tile[r + i * 16][c4 + 1] = vv[1];
    tile[r + i * 16][c4 + 2] = vv[2];
    tile[r + i * 16][c4 + 3] = vv[3];
  }
  __syncthreads();
#pragma unroll
  for (int i = 0; i < 4; ++i) {
    int nrow = r + i * 16;
    u16x4 o;
#pragma unroll
    for (int j = 0; j < 4; ++j) o[j] = f2b(tile[c4 + j][nrow]);
    *(u16x4*)(Wt + (size_t)(n0 + nrow) * dim + k0 + c4) = o;
  }
}

// ---------------- fold proj into Wq/Wk ----------------
__global__ void __launch_bounds__(256) fold_w(const float* __restrict__ Wq,
                                              const float* __restrict__ Wk,
                                              const float* __restrict__ proj,
                                              u16* __restrict__ WqkvT) {
  __shared__ float Wt[64][65];
  __shared__ float P[64][64];
  const int t = threadIdx.x;
  const int kbase = blockIdx.x * 64, h = blockIdx.y, sel = blockIdx.z;
  const float* W = sel ? Wk : Wq;
  {
    int row = t >> 2, cb = (t & 3) * 16;
#pragma unroll
    for (int i = 0; i < 4; ++i) {
      f32x4 vv = *(const f32x4*)(W + (size_t)(kbase + row) * 1024 + h * 64 + cb + i * 4);
      Wt[row][cb + i * 4 + 0] = vv[0]; Wt[row][cb + i * 4 + 1] = vv[1];
      Wt[row][cb + i * 4 + 2] = vv[2]; Wt[row][cb + i * 4 + 3] = vv[3];
      f32x4 pp = *(const f32x4*)(proj + (size_t)row * 64 + cb + i * 4);
      P[row][cb + i * 4 + 0] = pp[0]; P[row][cb + i * 4 + 1] = pp[1];
      P[row][cb + i * 4 + 2] = pp[2]; P[row][cb + i * 4 + 3] = pp[3];
    }
  }
  __syncthreads();
  const int kk = t & 63, fg = (t >> 6) * 16;
  float acc[16] = {};
  for (int d = 0; d < 64; ++d) {
    float w = Wt[kk][d];
#pragma unroll
    for (int ff = 0; ff < 16; ++ff) acc[ff] = fmaf(w, P[d][fg + ff], acc[ff]);
  }
#pragma unroll
  for (int ff = 0; ff < 16; ++ff)
    WqkvT[(size_t)(sel * 1024 + h * 64 + fg + ff) * 1024 + kbase + kk] = f2b(acc[ff]);
}

// ---------------- 256x256 BK=64 single-barrier-per-tile bf16 MFMA GEMM ----------------
// 512 thr = 8 waves (2M x 4N); per-wave C = 128x64 (8x4 frags of 16x16x32).
// Fragment state = round-1's 64 VGPR exactly (af 32, bl 16, bh 16): no spill
// (round-2 lesson: acc=128 AGPR leaves <=128 VGPR; 4 live sets spilled to scratch).
// Cluster order (M0,L)(M0,H)(M1,L)(M1,H) gives single-buffer lifetimes where all
// reads but af-M1 issue under a prior MFMA cluster:
//   bl(t+1) under C4; af-M0(t+1), bh(t+1) at tile tail (complete under C1/C2 via
//   counted lgkmcnt(4) at C1); af-M1(t) is the one exposed lgkm stall per tile.
// One vmcnt(0)+s_barrier per tile (between C3 and C4): proves (a) all waves'
// buf(t) ds_reads done (each waited lgkm pre-C3) -> WAR-safe to stage t+2 into
// buf(t); (b) all waves' t+1 stages landed -> RAW-safe to read buf(t+1).
template <int NB, bool QKV>
__global__ void __launch_bounds__(512) gemm256(const u16* __restrict__ Ax,
                                               const u16* __restrict__ Bt,
                                               u16* __restrict__ qo, u16* __restrict__ ko,
                                               u16* __restrict__ vo,
                                               float* __restrict__ Cf,
                                               const float* __restrict__ bias) {
  extern __shared__ __align__(16) u16 lds[];
  const int tid = threadIdx.x;
  // XCD swizzle: flat&7 = xcd; per XCD 16 m-blocks as 2 chunks of 8; n-major groups.
  const int flat = blockIdx.x;
  const int xcd = flat & 7, slot = flat >> 3;
  const int pos = slot & 7, g = slot >> 3;
  const int nc = g % NB, mc = g / NB;
  const int m0 = (xcd * 16 + mc * 8 + pos) * 256;
  const int n0 = nc * 256;
  const int w = tid >> 6, l = tid & 63, quad = l >> 4, lr = l & 15;
  const int wm = w >> 2, wn = w & 3;
  u16* const A0 = lds;                // buf0 A (2 halves of 8192 u16)
  u16* const B0 = lds + 16384;        // buf0 B
  u16* const A1 = lds + 32768;        // buf1 A
  u16* const B1 = lds + 49152;        // buf1 B
  // per-thread constant swizzled k-columns (u16 units) for the two ks slots
  const int c0 = ((quad * 16) ^ ((lr & 7) << 4)) >> 1;
  const int c1 = ((64 + quad * 16) ^ ((lr & 7) << 4)) >> 1;
  // staging: thread covers row rst (+64 for 2nd load), source col pre-swizzled
  const int rst = tid >> 3;
  const int ksw8 = ((tid & 7) ^ (rst & 7)) * 8;
  const int tid8 = tid * 8;

  f32x4 acc[8][4] = {};
  bf16x8 af[4][2];   // one M-half of A (4 m-frags x 2 ks)
  bf16x8 bl[2][2];   // B n-frags 0,1
  bf16x8 bh[2][2];   // B n-frags 2,3

#define STG(SRC, ROW0, KT, DST) do {                                         \
    const u16* s_ = (SRC) + (size_t)((ROW0) + rst) * 1024 + (KT) + ksw8;     \
    g2l16(s_, (DST) + tid8);                                                 \
    g2l16(s_ + 64 * 1024, (DST) + 4096 + tid8);                              \
  } while (0)

#define RD_A(BASE, MH) do {                                                  \
    const u16* ap_ = (BASE) + wm * 8192 + (MH) * 4096;                       \
    _Pragma("unroll")                                                        \
    for (int ii = 0; ii < 4; ++ii) {                                         \
      const int ro_ = (ii * 16 + lr) * 64;                                   \
      af[ii][0] = *(const bf16x8*)(ap_ + ro_ + c0);                          \
      af[ii][1] = *(const bf16x8*)(ap_ + ro_ + c1);                          \
    } } while (0)

#define RD_B(DST2, BASE, J0) do {                                            \
    const u16* bp_ = (BASE) + (wn >> 1) * 8192 + (wn & 1) * 4096;            \
    _Pragma("unroll")                                                        \
    for (int jj = 0; jj < 2; ++jj) {                                         \
      const int ro_ = (((J0) + jj) * 16 + lr) * 64;                          \
      DST2[jj][0] = *(const bf16x8*)(bp_ + ro_ + c0);                        \
      DST2[jj][1] = *(const bf16x8*)(bp_ + ro_ + c1);                        \
    } } while (0)

#define CL(MH, BF2, NH) do {                                                 \
    __builtin_amdgcn_s_setprio(1);                                           \
    _Pragma("unroll")                                                        \
    for (int ii = 0; ii < 4; ++ii)                                           \
      _Pragma("unroll")                                                      \
      for (int jj = 0; jj < 2; ++jj)                                         \
        _Pragma("unroll")                                                    \
        for (int ks = 0; ks < 2; ++ks)                                       \
          acc[(MH) * 4 + ii][(NH) * 2 + jj] =                                \
              __builtin_amdgcn_mfma_f32_16x16x32_bf16(                       \
                  af[ii][ks], BF2[jj][ks],                                   \
                  acc[(MH) * 4 + ii][(NH) * 2 + jj], 0, 0, 0);               \
    __builtin_amdgcn_s_setprio(0);                                           \
  } while (0)

#define SB0() __builtin_amdgcn_sched_barrier(0)
#define WAIT_LGKM(N) do { asm volatile("s_waitcnt lgkmcnt(" #N ")" ::: "memory"); SB0(); } while (0)
#define WAIT_VM0()   do { asm volatile("s_waitcnt vmcnt(0)" ::: "memory"); SB0(); } while (0)
#define BARRIER()    do { asm volatile("s_barrier" ::: "memory"); SB0(); } while (0)

  // prologue: stage tiles 0,1; prove tile 0 resident chip-wide; preload tile-0 frags
  STG(Ax, m0, 0, A0); STG(Ax, m0 + 128, 0, A0 + 8192);
  STG(Bt, n0, 0, B0); STG(Bt, n0 + 128, 0, B0 + 8192);
  STG(Ax, m0, 64, A1); STG(Ax, m0 + 128, 64, A1 + 8192);
  STG(Bt, n0, 64, B1); STG(Bt, n0 + 128, 64, B1 + 8192);
  asm volatile("s_waitcnt vmcnt(8)" ::: "memory");
  SB0();
  BARRIER();
  RD_B(bl, B0, 0);   // lgkm queue tail order must be [bl(4), af(8), bh(4)]
  RD_A(A0, 0);
  RD_B(bh, B0, 2);
  SB0();

#pragma unroll
  for (int t = 0; t < 16; ++t) {
    u16* const Ac = (t & 1) ? A1 : A0;
    u16* const Bc = (t & 1) ? B1 : B0;
    u16* const An = (t & 1) ? A0 : A1;
    u16* const Bn = (t & 1) ? B0 : B1;
    // C1: M0 x L — wait bl+af done, bh may still be in flight
    WAIT_LGKM(4);
    CL(0, bl, 0);
    // C2: M0 x H — drain bh (issued a full tile ago; ~free)
    WAIT_LGKM(0);
    CL(0, bh, 1);
    SB0();
    // af buffer dead -> pull M1(t); the one exposed lgkm stall per tile
    RD_A(Ac, 1);
    WAIT_LGKM(0);
    CL(1, bl, 0);
    SB0();
    if (t < 15) {
      WAIT_VM0();        // my t+1 stages landed (issued one tile ago)
      BARRIER();         // all: buf(t) reads done + everyone's t+1 stages landed
      if (t < 14) {      // stage t+2 into the just-freed current buffer
        STG(Ax, m0,       (t + 2) * 64, Ac);
        STG(Ax, m0 + 128, (t + 2) * 64, Ac + 8192);
        STG(Bt, n0,       (t + 2) * 64, Bc);
        STG(Bt, n0 + 128, (t + 2) * 64, Bc + 8192);
      }
      RD_B(bl, Bn, 0);   // bl(t+1), hides under C4
      SB0();
    }
    CL(1, bh, 1);
    SB0();
    if (t < 15) {
      RD_A(An, 0);       // af-M0(t+1): completes under next C1's counted wait
      RD_B(bh, Bn, 2);   // bh(t+1): completes under next C1/C2
      SB0();
    }
  }
#undef STG
#undef RD_A
#undef RD_B
#undef CL
#undef SB0
#undef WAIT_LGKM
#undef WAIT_VM0
#undef BARRIER

  const int rbase = m0 + wm * 128 + quad * 4;
  if (QKV) {
    const int sel = n0 >> 10;
    u16* dst = (sel == 0) ? qo : ((sel == 1) ? ko : vo);
    const int cb = (n0 & 1023) + wn * 64 + lr;
#pragma unroll
    for (int mi = 0; mi < 8; ++mi)
#pragma unroll
      for (int nj = 0; nj < 4; ++nj)
#pragma unroll
        for (int rr = 0; rr < 4; ++rr) {
          int row = rbase + mi * 16 + rr;
          float v = acc[mi][nj][rr];
          if (sel < 2) v = fmaxf(v, 0.0f) + FLA_EPS;
          dst[(size_t)row * 1024 + cb + nj * 16] = f2b(v);
        }
  } else {
    const int cb = n0 + wn * 64 + lr;
#pragma unroll
    for (int mi = 0; mi < 8; ++mi)
#pragma unroll
      for (int nj = 0; nj < 4; ++nj)
#pragma unroll
        for (int rr = 0; rr < 4; ++rr) {
          int row = rbase + mi * 16 + rr;
          Cf[(size_t)row * 1024 + cb + nj * 16] = acc[mi][nj][rr] + bias[cb + nj * 16];
        }
  }
}

// ---------------- kv partials ----------------
__global__ void __launch_bounds__(256) kv_partial(const u16* __restrict__ kf,
                                                  const u16* __restrict__ v,
                                                  float* __restrict__ part,
                                                  float* __restrict__ ksum_p) {
  const int t = threadIdx.x;
  const int bh = blockIdx.x, b = bh >> 4, h = bh & 15;
  const int w = t >> 6, l = t & 63;
  const int sub = blockIdx.y * 4 + w;
  const int f0 = (l >> 3) * 8, d0 = (l & 7) * 8;
  const size_t rowbase = ((size_t)b * 8192 + (size_t)sub * 256) * 1024 + h * 64;
  float acc[8][8] = {};
  float ks[8] = {};
#pragma unroll 2
  for (int n = 0; n < 256; ++n) {
    u16x8 ka = *(const u16x8*)(kf + rowbase + (size_t)n * 1024 + f0);
    u16x8 va = *(const u16x8*)(v + rowbase + (size_t)n * 1024 + d0);
    float kff[8], vf[8];
#pragma unroll
    for (int i = 0; i < 8; ++i) { kff[i] = b2f(ka[i]); vf[i] = b2f(va[i]); }
#pragma unroll
    for (int i = 0; i < 8; ++i) {
      ks[i] += kff[i];
#pragma unroll
      for (int j = 0; j < 8; ++j) acc[i][j] = fmaf(kff[i], vf[j], acc[i][j]);
    }
  }
  float* pb = part + ((size_t)bh * 32 + sub) * 4096;
#pragma unroll
  for (int j = 0; j < 8; ++j)
#pragma unroll
    for (int i = 0; i < 8; i += 4) {
      f32x4 vv = { acc[i][j], acc[i + 1][j], acc[i + 2][j], acc[i + 3][j] };
      *(f32x4*)(pb + (d0 + j) * 64 + f0 + i) = vv;
    }
  if (d0 == 0) {
    float* kp = ksum_p + ((size_t)bh * 32 + sub) * 64 + f0;
    f32x4 a = { ks[0], ks[1], ks[2], ks[3] }, bq = { ks[4], ks[5], ks[6], ks[7] };
    *(f32x4*)(kp) = a; *(f32x4*)(kp + 4) = bq;
  }
}

__global__ void __launch_bounds__(256) reduce_kv(const float* __restrict__ part,
                                                 float* __restrict__ kvT) {
  int i = blockIdx.x * 256 + threadIdx.x;
  int bh = i >> 12, dfi = i & 4095;
  const float* p = part + (size_t)bh * 32 * 4096 + dfi;
  float s = 0.f;
#pragma unroll
  for (int sub = 0; sub < 32; ++sub) s += p[(size_t)sub * 4096];
  kvT[i] = s;
}

// ---------------- num/den + normalize ----------------
__global__ void __launch_bounds__(256) num_den(const u16* __restrict__ qf,
                                               const float* __restrict__ kvT,
                                               const float* __restrict__ ksum_p,
                                               u16* __restrict__ outI) {
  __shared__ __align__(16) u16 As[128 * 64];
  __shared__ __align__(16) u16 Bs[64 * 64];
  __shared__ float ksum_s[64];
  __shared__ float den_s[128];
  const int t = threadIdx.x;
  const size_t tok0 = (size_t)blockIdx.x * 128;
  const int h = blockIdx.y;
  const int bh = (blockIdx.x >> 6) * 16 + h;
  const int w = t >> 6, l = t & 63, quad = l >> 4, lr = l & 15;
  const int trow = t >> 3, tcol = (t & 7) * 8;
#pragma unroll
  for (int i = 0; i < 4; ++i) {
    int r = i * 32 + trow;
    g2l16(qf + (tok0 + r) * 1024 + h * 64 + tcol, &As[r * 64 + tcol]);
  }
  {
    const float* kvb = kvT + (size_t)bh * 4096;
    int d = t >> 2, cb = (t & 3) * 16;
    u16x8 o0, o1;
#pragma unroll
    for (int q4 = 0; q4 < 2; ++q4) {
      f32x4 vv = *(const f32x4*)(kvb + d * 64 + cb + q4 * 4);
      o0[q4 * 4 + 0] = f2b(vv[0]); o0[q4 * 4 + 1] = f2b(vv[1]);
      o0[q4 * 4 + 2] = f2b(vv[2]); o0[q4 * 4 + 3] = f2b(vv[3]);
    }
#pragma unroll
    for (int q4 = 0; q4 < 2; ++q4) {
      f32x4 vv = *(const f32x4*)(kvb + d * 64 + cb + 8 + q4 * 4);
      o1[q4 * 4 + 0] = f2b(vv[0]); o1[q4 * 4 + 1] = f2b(vv[1]);
      o1[q4 * 4 + 2] = f2b(vv[2]); o1[q4 * 4 + 3] = f2b(vv[3]);
    }
    *(u16x8*)&Bs[d * 64 + cb] = o0;
    *(u16x8*)&Bs[d * 64 + cb + 8] = o1;
  }
  if (t < 64) {
    float s = 0.f;
    const float* kp = ksum_p + (size_t)bh * 32 * 64 + t;
#pragma unroll
    for (int sub = 0; sub < 32; ++sub) s += kp[(size_t)sub * 64];
    ksum_s[t] = s;
  }
  __syncthreads();
  if (t < 128) {
    float d = FLA_EPS;
#pragma unroll
    for (int jj = 0; jj < 64; ++jj) {
      int f = (t + jj) & 63;
      d += b2f(As[t * 64 + f]) * ksum_s[f];
    }
    den_s[t] = d;
  }
  __syncthreads();
  f32x4 acc[2][4] = {};
  const int wrow = w * 32;
#pragma unroll
  for (int ks = 0; ks < 2; ++ks) {
    bf16x8 af[2], bfr[4];
#pragma unroll
    for (int i = 0; i < 2; ++i)
      af[i] = *(const bf16x8*)&As[(wrow + i * 16 + lr) * 64 + ks * 32 + quad * 8];
#pragma unroll
    for (int j = 0; j < 4; ++j)
      bfr[j] = *(const bf16x8*)&Bs[(j * 16 + lr) * 64 + ks * 32 + quad * 8];
#pragma unroll
    for (int i = 0; i < 2; ++i)
#pragma unroll
      for (int j = 0; j < 4; ++j)
        acc[i][j] = __builtin_amdgcn_mfma_f32_16x16x32_bf16(af[i], bfr[j], acc[i][j], 0, 0, 0);
  }
#pragma unroll
  for (int i = 0; i < 2; ++i)
#pragma unroll
    for (int j = 0; j < 4; ++j)
#pragma unroll
      for (int rr = 0; rr < 4; ++rr) {
        int rloc = wrow + i * 16 + quad * 4 + rr;
        float v = acc[i][j][rr] / den_s[rloc];
        outI[(tok0 + rloc) * 1024 + h * 64 + j * 16 + lr] = f2b(v);
      }
}

extern "C" void kernel_launch(void* const* d_in, const int* in_sizes, int n_in,
                              void* d_out, int out_size, void* d_ws, size_t ws_size,
                              hipStream_t stream) {
  const float* x    = (const float*)d_in[0];
  const float* Wq   = (const float*)d_in[1];
  const float* Wk   = (const float*)d_in[2];
  const float* Wv   = (const float*)d_in[3];
  const float* proj = (const float*)d_in[4];
  const float* Wo   = (const float*)d_in[5];
  const float* bo   = (const float*)d_in[6];
  float* out = (float*)d_out;

  char* ws = (char*)d_ws;
  const size_t SZ = 1ull << 26;
  u16* xb     = (u16*)(ws + 0);
  u16* qb     = (u16*)(ws + SZ);
  u16* kb     = (u16*)(ws + 2 * SZ);
  u16* vb     = (u16*)(ws + 3 * SZ);
  u16* WqkvT  = (u16*)(ws + 4 * SZ);
  u16* woT    = (u16*)(ws + 4 * SZ + 0x600000);
  float* part   = (float*)(ws + 4 * SZ + 0x800000);
  float* ksum_p = (float*)(ws + 4 * SZ + 0x800000 + 0x2000000);
  float* kvT    = (float*)(ws + 4 * SZ + 0x800000 + 0x2080000);

  static int attr_done = 0;
  if (!attr_done) {
    (void)hipFuncSetAttribute((const void*)gemm256<12, true>,
                              hipFuncAttributeMaxDynamicSharedMemorySize, 131072);
    (void)hipFuncSetAttribute((const void*)gemm256<4, false>,
                              hipFuncAttributeMaxDynamicSharedMemorySize, 131072);
    attr_done = 1;
  }

  cast_f32_bf16<<<16384, 256, 0, stream>>>(x, xb);
  fold_w<<<dim3(16, 16, 2), 256, 0, stream>>>(Wq, Wk, proj, WqkvT);
  transpose_cast<<<dim3(16, 16), 256, 0, stream>>>(Wv, WqkvT + (size_t)2048 * 1024, 1024);
  transpose_cast<<<dim3(16, 16), 256, 0, stream>>>(Wo, woT, 1024);
  gemm256<12, true><<<1536, 512, 131072, stream>>>(xb, WqkvT, qb, kb, vb, nullptr, nullptr);
  kv_partial<<<dim3(64, 8), 256, 0, stream>>>(kb, vb, part, ksum_p);
  reduce_kv<<<1024, 256, 0, stream>>>(part, kvT);
  num_den<<<dim3(256, 16), 256, 0, stream>>>(qb, kvT, ksum_p, xb);
  gemm256<4, false><<<512, 512, 131072, stream>>>(xb, woT, nullptr, nullptr, nullptr, out, bo);
}

// Round 5
// 586.344 us; speedup vs baseline: 1.5251x; 1.1172x over previous
//
#include <hip/hip_runtime.h>

typedef unsigned short u16;
typedef unsigned int u32;
typedef __attribute__((ext_vector_type(4))) float f32x4;
typedef __attribute__((ext_vector_type(4))) u16 u16x4;
typedef __attribute__((ext_vector_type(8))) u16 u16x8;
typedef __attribute__((ext_vector_type(8))) __bf16 bf16x8;

#define FLA_EPS 1e-6f

__device__ __forceinline__ u16 f2b(float f) {
  union { float f; u32 u; } v; v.f = f;
  u32 r = v.u + 0x7FFFu + ((v.u >> 16) & 1u);
  return (u16)(r >> 16);
}
__device__ __forceinline__ float b2f(u16 h) {
  union { u32 u; float f; } v; v.u = ((u32)h) << 16; return v.f;
}
__device__ __forceinline__ float bsum8(bf16x8 v) {
  union { bf16x8 b; u16x8 u; } x; x.b = v;
  float s = 0.f;
#pragma unroll
  for (int e = 0; e < 8; ++e) s += b2f(x.u[e]);
  return s;
}
__device__ __forceinline__ void g2l16(const void* g, void* l) {
  __builtin_amdgcn_global_load_lds((__attribute__((address_space(1))) void*)g,
                                   (__attribute__((address_space(3))) void*)l,
                                   16, 0, 0);
}

// ---------------- cast x fp32 -> bf16 ----------------
__global__ void __launch_bounds__(256) cast_f32_bf16(const float* __restrict__ in,
                                                     u16* __restrict__ out) {
  size_t i = (size_t)blockIdx.x * 256 + threadIdx.x;
  const f32x4* p = (const f32x4*)in + i * 2;
  f32x4 a = p[0], b = p[1];
  u16x8 r;
  r[0] = f2b(a[0]); r[1] = f2b(a[1]); r[2] = f2b(a[2]); r[3] = f2b(a[3]);
  r[4] = f2b(b[0]); r[5] = f2b(b[1]); r[6] = f2b(b[2]); r[7] = f2b(b[3]);
  ((u16x8*)out)[i] = r;
}

// ---------------- transpose + cast: Wt[n][k] = bf16(W[k][n]) ----------------
__global__ void __launch_bounds__(256) transpose_cast(const float* __restrict__ W,
                                                      u16* __restrict__ Wt, int dim) {
  __shared__ float tile[64][65];
  const int t = threadIdx.x;
  const int k0 = blockIdx.x * 64, n0 = blockIdx.y * 64;
  const int r = t >> 4, c4 = (t & 15) * 4;
#pragma unroll
  for (int i = 0; i < 4; ++i) {
    f32x4 vv = *(const f32x4*)(W + (size_t)(k0 + r + i * 16) * dim + n0 + c4);
    tile[r + i * 16][c4 + 0] = vv[0];
    tile[r + i * 16][c4 + 1] = vv[1];
    tile[r + i * 16][c4 + 2] = vv[2];
    tile[r + i * 16][c4 + 3] = vv[3];
  }
  __syncthreads();
#pragma unroll
  for (int i = 0; i < 4; ++i) {
    int nrow = r + i * 16;
    u16x4 o;
#pragma unroll
    for (int j = 0; j < 4; ++j) o[j] = f2b(tile[c4 + j][nrow]);
    *(u16x4*)(Wt + (size_t)(n0 + nrow) * dim + k0 + c4) = o;
  }
}

// ---------------- fold proj into Wq/Wk ----------------
__global__ void __launch_bounds__(256) fold_w(const float* __restrict__ Wq,
                                              const float* __restrict__ Wk,
                                              const float* __restrict__ proj,
                                              u16* __restrict__ WqkvT) {
  __shared__ float Wt[64][65];
  __shared__ float P[64][64];
  const int t = threadIdx.x;
  const int kbase = blockIdx.x * 64, h = blockIdx.y, sel = blockIdx.z;
  const float* W = sel ? Wk : Wq;
  {
    int row = t >> 2, cb = (t & 3) * 16;
#pragma unroll
    for (int i = 0; i < 4; ++i) {
      f32x4 vv = *(const f32x4*)(W + (size_t)(kbase + row) * 1024 + h * 64 + cb + i * 4);
      Wt[row][cb + i * 4 + 0] = vv[0]; Wt[row][cb + i * 4 + 1] = vv[1];
      Wt[row][cb + i * 4 + 2] = vv[2]; Wt[row][cb + i * 4 + 3] = vv[3];
      f32x4 pp = *(const f32x4*)(proj + (size_t)row * 64 + cb + i * 4);
      P[row][cb + i * 4 + 0] = pp[0]; P[row][cb + i * 4 + 1] = pp[1];
      P[row][cb + i * 4 + 2] = pp[2]; P[row][cb + i * 4 + 3] = pp[3];
    }
  }
  __syncthreads();
  const int kk = t & 63, fg = (t >> 6) * 16;
  float acc[16] = {};
  for (int d = 0; d < 64; ++d) {
    float w = Wt[kk][d];
#pragma unroll
    for (int ff = 0; ff < 16; ++ff) acc[ff] = fmaf(w, P[d][fg + ff], acc[ff]);
  }
#pragma unroll
  for (int ff = 0; ff < 16; ++ff)
    WqkvT[(size_t)(sel * 1024 + h * 64 + fg + ff) * 1024 + kbase + kk] = f2b(acc[ff]);
}

// ---------------- 256x256 BK=64 single-barrier-per-tile bf16 MFMA GEMM ----------------
// K-loop identical to round-3 (proven: 1000 TF, no spill, 0 bank conflicts).
// QKV k/v epilogue: bounce C-tile through the (free) 128KB LDS with an XOR-swizzled
// transpose, then write kT[b,h,f,n] / vT[b,h,d,n] (n-contiguous, coalesced 16B
// stores) for the MFMA kv kernel. q keeps [token][1024] (num_den wants rows).
// ROUND-4 BUG FIX: q branch was missing the (n0 & 1023) column offset -> all four
// q n-chunks raced into cols 0..255. Restored.
template <int NB, bool QKV>
__global__ void __launch_bounds__(512) gemm256(const u16* __restrict__ Ax,
                                               const u16* __restrict__ Bt,
                                               u16* __restrict__ qo, u16* __restrict__ ko,
                                               u16* __restrict__ vo,
                                               float* __restrict__ Cf,
                                               const float* __restrict__ bias) {
  extern __shared__ __align__(16) u16 lds[];
  const int tid = threadIdx.x;
  // XCD swizzle: flat&7 = xcd; per XCD 16 m-blocks as 2 chunks of 8; n-major groups.
  const int flat = blockIdx.x;
  const int xcd = flat & 7, slot = flat >> 3;
  const int pos = slot & 7, g = slot >> 3;
  const int nc = g % NB, mc = g / NB;
  const int m0 = (xcd * 16 + mc * 8 + pos) * 256;
  const int n0 = nc * 256;
  const int w = tid >> 6, l = tid & 63, quad = l >> 4, lr = l & 15;
  const int wm = w >> 2, wn = w & 3;
  u16* const A0 = lds;                // buf0 A (2 halves of 8192 u16)
  u16* const B0 = lds + 16384;        // buf0 B
  u16* const A1 = lds + 32768;        // buf1 A
  u16* const B1 = lds + 49152;        // buf1 B
  const int c0 = ((quad * 16) ^ ((lr & 7) << 4)) >> 1;
  const int c1 = ((64 + quad * 16) ^ ((lr & 7) << 4)) >> 1;
  const int rst = tid >> 3;
  const int ksw8 = ((tid & 7) ^ (rst & 7)) * 8;
  const int tid8 = tid * 8;

  f32x4 acc[8][4] = {};
  bf16x8 af[4][2];   // one M-half of A (4 m-frags x 2 ks)
  bf16x8 bl[2][2];   // B n-frags 0,1
  bf16x8 bh[2][2];   // B n-frags 2,3

#define STG(SRC, ROW0, KT, DST) do {                                         \
    const u16* s_ = (SRC) + (size_t)((ROW0) + rst) * 1024 + (KT) + ksw8;     \
    g2l16(s_, (DST) + tid8);                                                 \
    g2l16(s_ + 64 * 1024, (DST) + 4096 + tid8);                              \
  } while (0)

#define RD_A(BASE, MH) do {                                                  \
    const u16* ap_ = (BASE) + wm * 8192 + (MH) * 4096;                       \
    _Pragma("unroll")                                                        \
    for (int ii = 0; ii < 4; ++ii) {                                         \
      const int ro_ = (ii * 16 + lr) * 64;                                   \
      af[ii][0] = *(const bf16x8*)(ap_ + ro_ + c0);                          \
      af[ii][1] = *(const bf16x8*)(ap_ + ro_ + c1);                          \
    } } while (0)

#define RD_B(DST2, BASE, J0) do {                                            \
    const u16* bp_ = (BASE) + (wn >> 1) * 8192 + (wn & 1) * 4096;            \
    _Pragma("unroll")                                                        \
    for (int jj = 0; jj < 2; ++jj) {                                         \
      const int ro_ = (((J0) + jj) * 16 + lr) * 64;                          \
      DST2[jj][0] = *(const bf16x8*)(bp_ + ro_ + c0);                        \
      DST2[jj][1] = *(const bf16x8*)(bp_ + ro_ + c1);                        \
    } } while (0)

#define CL(MH, BF2, NH) do {                                                 \
    __builtin_amdgcn_s_setprio(1);                                           \
    _Pragma("unroll")                                                        \
    for (int ii = 0; ii < 4; ++ii)                                           \
      _Pragma("unroll")                                                      \
      for (int jj = 0; jj < 2; ++jj)                                         \
        _Pragma("unroll")                                                    \
        for (int ks = 0; ks < 2; ++ks)                                       \
          acc[(MH) * 4 + ii][(NH) * 2 + jj] =                                \
              __builtin_amdgcn_mfma_f32_16x16x32_bf16(                       \
                  af[ii][ks], BF2[jj][ks],                                   \
                  acc[(MH) * 4 + ii][(NH) * 2 + jj], 0, 0, 0);               \
    __builtin_amdgcn_s_setprio(0);                                           \
  } while (0)

#define SB0() __builtin_amdgcn_sched_barrier(0)
#define WAIT_LGKM(N) do { asm volatile("s_waitcnt lgkmcnt(" #N ")" ::: "memory"); SB0(); } while (0)
#define WAIT_VM0()   do { asm volatile("s_waitcnt vmcnt(0)" ::: "memory"); SB0(); } while (0)
#define BARRIER()    do { asm volatile("s_barrier" ::: "memory"); SB0(); } while (0)

  // prologue: stage tiles 0,1; prove tile 0 resident chip-wide; preload tile-0 frags
  STG(Ax, m0, 0, A0); STG(Ax, m0 + 128, 0, A0 + 8192);
  STG(Bt, n0, 0, B0); STG(Bt, n0 + 128, 0, B0 + 8192);
  STG(Ax, m0, 64, A1); STG(Ax, m0 + 128, 64, A1 + 8192);
  STG(Bt, n0, 64, B1); STG(Bt, n0 + 128, 64, B1 + 8192);
  asm volatile("s_waitcnt vmcnt(8)" ::: "memory");
  SB0();
  BARRIER();
  RD_B(bl, B0, 0);   // lgkm queue tail order must be [bl(4), af(8), bh(4)]
  RD_A(A0, 0);
  RD_B(bh, B0, 2);
  SB0();

#pragma unroll
  for (int t = 0; t < 16; ++t) {
    u16* const Ac = (t & 1) ? A1 : A0;
    u16* const Bc = (t & 1) ? B1 : B0;
    u16* const An = (t & 1) ? A0 : A1;
    u16* const Bn = (t & 1) ? B0 : B1;
    WAIT_LGKM(4);
    CL(0, bl, 0);
    WAIT_LGKM(0);
    CL(0, bh, 1);
    SB0();
    RD_A(Ac, 1);
    WAIT_LGKM(0);
    CL(1, bl, 0);
    SB0();
    if (t < 15) {
      WAIT_VM0();
      BARRIER();
      if (t < 14) {
        STG(Ax, m0,       (t + 2) * 64, Ac);
        STG(Ax, m0 + 128, (t + 2) * 64, Ac + 8192);
        STG(Bt, n0,       (t + 2) * 64, Bc);
        STG(Bt, n0 + 128, (t + 2) * 64, Bc + 8192);
      }
      RD_B(bl, Bn, 0);
      SB0();
    }
    CL(1, bh, 1);
    SB0();
    if (t < 15) {
      RD_A(An, 0);
      RD_B(bh, Bn, 2);
      SB0();
    }
  }
#undef STG
#undef RD_A
#undef RD_B
#undef CL
#undef WAIT_LGKM
#undef WAIT_VM0
#undef BARRIER

  const int rbase = m0 + wm * 128 + quad * 4;
  if (QKV) {
    const int sel = n0 >> 10;
    if (sel == 0) {
      // q: direct stores, layout [token][1024] (num_den reads rows)
      const int cb = (n0 & 1023) + wn * 64 + lr;
#pragma unroll
      for (int mi = 0; mi < 8; ++mi)
#pragma unroll
        for (int nj = 0; nj < 4; ++nj)
#pragma unroll
          for (int rr = 0; rr < 4; ++rr) {
            int row = rbase + mi * 16 + rr;
            float v = fmaxf(acc[mi][nj][rr], 0.0f) + FLA_EPS;
            qo[(size_t)row * 1024 + cb + nj * 16] = f2b(v);
          }
    } else {
      // k/v: LDS-bounce transpose -> kT/vT[b,h,f,n] (n contiguous).
      // LDS_T[c][r] over full 128KB, chunk-swizzled: u16 addr =
      //   c*256 + (((r>>3)^(c&7))<<3) + (r&7)   (c,r in [0,256))
      const bool isK = (sel == 1);
      __syncthreads();   // all waves' K-loop LDS reads retired; DMA drained @t=14
#pragma unroll
      for (int mi = 0; mi < 8; ++mi)
#pragma unroll
        for (int nj = 0; nj < 4; ++nj) {
          const int r0 = wm * 128 + mi * 16 + quad * 4;   // r0&7 = (quad&1)*4
          const int c = wn * 64 + nj * 16 + lr;
          u16x4 pk;
#pragma unroll
          for (int rr = 0; rr < 4; ++rr) {
            float v = acc[mi][nj][rr];
            if (isK) v = fmaxf(v, 0.0f) + FLA_EPS;
            pk[rr] = f2b(v);
          }
          *(u16x4*)&lds[c * 256 + (((r0 >> 3) ^ (c & 7)) << 3) + (r0 & 7)] = pk;
        }
      __syncthreads();
      u16* dstT = isK ? ko : vo;
      const int bI = m0 >> 13, s0 = m0 & 8191;
      const size_t cb0 = ((size_t)bI << 10) + (n0 & 1023);
#pragma unroll
      for (int i = 0; i < 16; ++i) {
        const int c = w * 32 + i * 2 + (l >> 5);
        const int u = (l & 31) ^ (c & 7);
        u16x8 vv = *(const u16x8*)&lds[c * 256 + u * 8];
        *(u16x8*)(dstT + (cb0 + c) * 8192 + s0 + (l & 31) * 8) = vv;
      }
    }
  } else {
#pragma unroll
    for (int mi = 0; mi < 8; ++mi)
#pragma unroll
      for (int nj = 0; nj < 4; ++nj) {
        const int cb = n0 + wn * 64 + nj * 16 + lr;
#pragma unroll
        for (int rr = 0; rr < 4; ++rr) {
          int row = rbase + mi * 16 + rr;
          Cf[(size_t)row * 1024 + cb] = acc[mi][nj][rr] + bias[cb];
        }
      }
  }
}

// ---------------- kv via MFMA: D[d][f] = sum_n vT[d][n] * kT[f][n] ----------------
// Per (bh, chunk of 1024 n): M=N=64, K=1024. Both operands natural k-contiguous rows.
// 4 waves partition (d,f) 2x2 (acc 2x2 frags = 16 AGPR). 16 double-buffered k-tiles
// of [64][64] per operand (8KB each, 32KB LDS -> 4 blocks/CU). ksum[f] = row-sums of
// kT accumulated from B-fragments (waves 0,1 cover f 0..63), quad-reduced via shfl.
__global__ void __launch_bounds__(256) kv_mfma(const u16* __restrict__ kT,
                                               const u16* __restrict__ vT,
                                               float* __restrict__ part,
                                               float* __restrict__ ksum_p) {
  __shared__ __align__(16) u16 Av[2][4096];
  __shared__ __align__(16) u16 Bk[2][4096];
  const int tid = threadIdx.x;
  const int bh = blockIdx.x, chunk = blockIdx.y;
  const size_t n0 = (size_t)chunk * 1024;
  const u16* vbp = vT + (size_t)bh * 64 * 8192;
  const u16* kbp = kT + (size_t)bh * 64 * 8192;
  const int w = tid >> 6, l = tid & 63, quad = l >> 4, lr = l & 15;
  const int wd = w >> 1, wf = w & 1;
  const int dstg = tid >> 3, kc = tid & 7;
  const int sc0 = (kc ^ (dstg & 7)) * 8;
  f32x4 acc[2][2] = {};
  float ksm[2] = {0.f, 0.f};

#define KVSTG(BUF, T) do {                                                    \
    const size_t off_ = n0 + (size_t)(T) * 64;                                \
    g2l16(vbp + (size_t)dstg * 8192 + off_ + sc0, &Av[BUF][tid8_]);           \
    g2l16(vbp + (size_t)(dstg + 32) * 8192 + off_ + sc0, &Av[BUF][2048 + tid8_]); \
    g2l16(kbp + (size_t)dstg * 8192 + off_ + sc0, &Bk[BUF][tid8_]);           \
    g2l16(kbp + (size_t)(dstg + 32) * 8192 + off_ + sc0, &Bk[BUF][2048 + tid8_]); \
  } while (0)
  const int tid8_ = tid * 8;

  KVSTG(0, 0);
  for (int t = 0; t < 16; ++t) {
    const int buf = t & 1;
    if (t < 15) {
      KVSTG(buf ^ 1, t + 1);
      asm volatile("s_waitcnt vmcnt(4)" ::: "memory");
    } else {
      asm volatile("s_waitcnt vmcnt(0)" ::: "memory");
    }
    __builtin_amdgcn_sched_barrier(0);
    __builtin_amdgcn_s_barrier();   // tile t resident everywhere; prev reads done
    bf16x8 av[2][2], bk[2][2];
#pragma unroll
    for (int di = 0; di < 2; ++di)
#pragma unroll
      for (int ks = 0; ks < 2; ++ks) {
        const int d = wd * 32 + di * 16 + lr;
        av[di][ks] = *(const bf16x8*)&Av[buf][d * 64 + ((ks * 4 + quad) ^ (d & 7)) * 8];
        const int f = wf * 32 + di * 16 + lr;
        bk[di][ks] = *(const bf16x8*)&Bk[buf][f * 64 + ((ks * 4 + quad) ^ (f & 7)) * 8];
      }
    asm volatile("s_waitcnt lgkmcnt(0)" ::: "memory");
    __builtin_amdgcn_sched_barrier(0);
#pragma unroll
    for (int di = 0; di < 2; ++di)
#pragma unroll
      for (int fj = 0; fj < 2; ++fj)
#pragma unroll
        for (int ks = 0; ks < 2; ++ks)
          acc[di][fj] = __builtin_amdgcn_mfma_f32_16x16x32_bf16(
              av[di][ks], bk[fj][ks], acc[di][fj], 0, 0, 0);
    if (w < 2) {   // ksum: waves 0,1 cover f 0..63 once (wd==0 slice)
#pragma unroll
      for (int fj = 0; fj < 2; ++fj) {
        ksm[fj] += bsum8(bk[fj][0]);
        ksm[fj] += bsum8(bk[fj][1]);
      }
    }
    __builtin_amdgcn_s_barrier();   // my reads of buf done -> safe to overwrite next iter
  }
#undef KVSTG

  float* pb = part + ((size_t)bh * 8 + chunk) * 4096;
#pragma unroll
  for (int di = 0; di < 2; ++di)
#pragma unroll
    for (int fj = 0; fj < 2; ++fj)
#pragma unroll
      for (int rr = 0; rr < 4; ++rr) {
        const int d = wd * 32 + di * 16 + quad * 4 + rr;
        const int f = wf * 32 + fj * 16 + lr;
        pb[d * 64 + f] = acc[di][fj][rr];
      }
  if (w < 2) {
#pragma unroll
    for (int fj = 0; fj < 2; ++fj) {
      float s = ksm[fj];
      s += __shfl_xor(s, 16, 64);
      s += __shfl_xor(s, 32, 64);
      if (l < 16)
        ksum_p[((size_t)bh * 8 + chunk) * 64 + wf * 32 + fj * 16 + l] = s;
    }
  }
}

__global__ void __launch_bounds__(256) reduce_kv(const float* __restrict__ part,
                                                 float* __restrict__ kvT) {
  int i = blockIdx.x * 256 + threadIdx.x;
  int bh = i >> 12, dfi = i & 4095;
  const float* p = part + (size_t)bh * 8 * 4096 + dfi;
  float s = 0.f;
#pragma unroll
  for (int sub = 0; sub < 8; ++sub) s += p[(size_t)sub * 4096];
  kvT[i] = s;
}

// ---------------- num/den + normalize ----------------
__global__ void __launch_bounds__(256) num_den(const u16* __restrict__ qf,
                                               const float* __restrict__ kvT,
                                               const float* __restrict__ ksum_p,
                                               u16* __restrict__ outI) {
  __shared__ __align__(16) u16 As[128 * 64];
  __shared__ __align__(16) u16 Bs[64 * 64];
  __shared__ float ksum_s[64];
  __shared__ float den_s[128];
  const int t = threadIdx.x;
  const size_t tok0 = (size_t)blockIdx.x * 128;
  const int h = blockIdx.y;
  const int bh = (blockIdx.x >> 6) * 16 + h;
  const int w = t >> 6, l = t & 63, quad = l >> 4, lr = l & 15;
  const int trow = t >> 3, tcol = (t & 7) * 8;
#pragma unroll
  for (int i = 0; i < 4; ++i) {
    int r = i * 32 + trow;
    g2l16(qf + (tok0 + r) * 1024 + h * 64 + tcol, &As[r * 64 + tcol]);
  }
  {
    const float* kvb = kvT + (size_t)bh * 4096;
    int d = t >> 2, cb = (t & 3) * 16;
    u16x8 o0, o1;
#pragma unroll
    for (int q4 = 0; q4 < 2; ++q4) {
      f32x4 vv = *(const f32x4*)(kvb + d * 64 + cb + q4 * 4);
      o0[q4 * 4 + 0] = f2b(vv[0]); o0[q4 * 4 + 1] = f2b(vv[1]);
      o0[q4 * 4 + 2] = f2b(vv[2]); o0[q4 * 4 + 3] = f2b(vv[3]);
    }
#pragma unroll
    for (int q4 = 0; q4 < 2; ++q4) {
      f32x4 vv = *(const f32x4*)(kvb + d * 64 + cb + 8 + q4 * 4);
      o1[q4 * 4 + 0] = f2b(vv[0]); o1[q4 * 4 + 1] = f2b(vv[1]);
      o1[q4 * 4 + 2] = f2b(vv[2]); o1[q4 * 4 + 3] = f2b(vv[3]);
    }
    *(u16x8*)&Bs[d * 64 + cb] = o0;
    *(u16x8*)&Bs[d * 64 + cb + 8] = o1;
  }
  if (t < 64) {
    float s = 0.f;
    const float* kp = ksum_p + (size_t)bh * 8 * 64 + t;
#pragma unroll
    for (int sub = 0; sub < 8; ++sub) s += kp[(size_t)sub * 64];
    ksum_s[t] = s;
  }
  __syncthreads();
  if (t < 128) {
    float d = FLA_EPS;
#pragma unroll
    for (int jj = 0; jj < 64; ++jj) {
      int f = (t + jj) & 63;
      d += b2f(As[t * 64 + f]) * ksum_s[f];
    }
    den_s[t] = d;
  }
  __syncthreads();
  f32x4 acc[2][4] = {};
  const int wrow = w * 32;
#pragma unroll
  for (int ks = 0; ks < 2; ++ks) {
    bf16x8 af[2], bfr[4];
#pragma unroll
    for (int i = 0; i < 2; ++i)
      af[i] = *(const bf16x8*)&As[(wrow + i * 16 + lr) * 64 + ks * 32 + quad * 8];
#pragma unroll
    for (int j = 0; j < 4; ++j)
      bfr[j] = *(const bf16x8*)&Bs[(j * 16 + lr) * 64 + ks * 32 + quad * 8];
#pragma unroll
    for (int i = 0; i < 2; ++i)
#pragma unroll
      for (int j = 0; j < 4; ++j)
        acc[i][j] = __builtin_amdgcn_mfma_f32_16x16x32_bf16(af[i], bfr[j], acc[i][j], 0, 0, 0);
  }
#pragma unroll
  for (int i = 0; i < 2; ++i)
#pragma unroll
    for (int j = 0; j < 4; ++j)
#pragma unroll
      for (int rr = 0; rr < 4; ++rr) {
        int rloc = wrow + i * 16 + quad * 4 + rr;
        float v = acc[i][j][rr] / den_s[rloc];
        outI[(tok0 + rloc) * 1024 + h * 64 + j * 16 + lr] = f2b(v);
      }
}

extern "C" void kernel_launch(void* const* d_in, const int* in_sizes, int n_in,
                              void* d_out, int out_size, void* d_ws, size_t ws_size,
                              hipStream_t stream) {
  const float* x    = (const float*)d_in[0];
  const float* Wq   = (const float*)d_in[1];
  const float* Wk   = (const float*)d_in[2];
  const float* Wv   = (const float*)d_in[3];
  const float* proj = (const float*)d_in[4];
  const float* Wo   = (const float*)d_in[5];
  const float* bo   = (const float*)d_in[6];
  float* out = (float*)d_out;

  char* ws = (char*)d_ws;
  const size_t SZ = 1ull << 26;
  u16* xb     = (u16*)(ws + 0);
  u16* qb     = (u16*)(ws + SZ);
  u16* kb     = (u16*)(ws + 2 * SZ);   // kT[b,h,f,n]
  u16* vb     = (u16*)(ws + 3 * SZ);   // vT[b,h,d,n]
  u16* WqkvT  = (u16*)(ws + 4 * SZ);
  u16* woT    = (u16*)(ws + 4 * SZ + 0x600000);
  float* part   = (float*)(ws + 4 * SZ + 0x800000);
  float* ksum_p = (float*)(ws + 4 * SZ + 0x800000 + 0x2000000);
  float* kvT    = (float*)(ws + 4 * SZ + 0x800000 + 0x2080000);

  static int attr_done = 0;
  if (!attr_done) {
    (void)hipFuncSetAttribute((const void*)gemm256<12, true>,
                              hipFuncAttributeMaxDynamicSharedMemorySize, 131072);
    (void)hipFuncSetAttribute((const void*)gemm256<4, false>,
                              hipFuncAttributeMaxDynamicSharedMemorySize, 131072);
    attr_done = 1;
  }

  cast_f32_bf16<<<16384, 256, 0, stream>>>(x, xb);
  fold_w<<<dim3(16, 16, 2), 256, 0, stream>>>(Wq, Wk, proj, WqkvT);
  transpose_cast<<<dim3(16, 16), 256, 0, stream>>>(Wv, WqkvT + (size_t)2048 * 1024, 1024);
  transpose_cast<<<dim3(16, 16), 256, 0, stream>>>(Wo, woT, 1024);
  gemm256<12, true><<<1536, 512, 131072, stream>>>(xb, WqkvT, qb, kb, vb, nullptr, nullptr);
  kv_mfma<<<dim3(64, 8), 256, 0, stream>>>(kb, vb, part, ksum_p);
  reduce_kv<<<1024, 256, 0, stream>>>(part, kvT);
  num_den<<<dim3(256, 16), 256, 0, stream>>>(qb, kvT, ksum_p, xb);
  gemm256<4, false><<<512, 512, 131072, stream>>>(xb, woT, nullptr, nullptr, nullptr, out, bo);
}

// Round 6
// 579.111 us; speedup vs baseline: 1.5441x; 1.0125x over previous
//
#include <hip/hip_runtime.h>

typedef unsigned short u16;
typedef unsigned int u32;
typedef __attribute__((ext_vector_type(4))) float f32x4;
typedef __attribute__((ext_vector_type(4))) u16 u16x4;
typedef __attribute__((ext_vector_type(8))) u16 u16x8;
typedef __attribute__((ext_vector_type(8))) __bf16 bf16x8;

#define FLA_EPS 1e-6f

__device__ __forceinline__ u16 f2b(float f) {
  union { float f; u32 u; } v; v.f = f;
  u32 r = v.u + 0x7FFFu + ((v.u >> 16) & 1u);
  return (u16)(r >> 16);
}
__device__ __forceinline__ float b2f(u16 h) {
  union { u32 u; float f; } v; v.u = ((u32)h) << 16; return v.f;
}
__device__ __forceinline__ float bsum8(bf16x8 v) {
  union { bf16x8 b; u16x8 u; } x; x.b = v;
  float s = 0.f;
#pragma unroll
  for (int e = 0; e < 8; ++e) s += b2f(x.u[e]);
  return s;
}
__device__ __forceinline__ void g2l16(const void* g, void* l) {
  __builtin_amdgcn_global_load_lds((__attribute__((address_space(1))) void*)g,
                                   (__attribute__((address_space(3))) void*)l,
                                   16, 0, 0);
}

// ---------------- fused prep: cast x, fold proj, transpose Wv/Wo, zero kv accum ----
// blockIdx ranges:
//   [0, 16384)        cast x fp32 -> bf16
//   [16384, 16896)    fold_w (Wq/Wk @ proj -> WqkvT rows, transposed)
//   [16896, 17152)    transpose_cast Wv -> WqkvT + 2048*1024
//   [17152, 17408)    transpose_cast Wo -> woT
//   [17408, 17668)    zero kvT (1MB) + ksum (16KB) accumulators
__global__ void __launch_bounds__(256) prep(const float* __restrict__ x,
                                            const float* __restrict__ Wq,
                                            const float* __restrict__ Wk,
                                            const float* __restrict__ Wv,
                                            const float* __restrict__ Wo,
                                            const float* __restrict__ proj,
                                            u16* __restrict__ xb,
                                            u16* __restrict__ WqkvT,
                                            u16* __restrict__ woT,
                                            float* __restrict__ zbase) {
  __shared__ __align__(16) char smem[33280];
  const int blk = blockIdx.x;
  const int t = threadIdx.x;
  if (blk < 16384) {
    // ---- cast ----
    size_t i = (size_t)blk * 256 + t;
    const f32x4* p = (const f32x4*)x + i * 2;
    f32x4 a = p[0], b = p[1];
    u16x8 r;
    r[0] = f2b(a[0]); r[1] = f2b(a[1]); r[2] = f2b(a[2]); r[3] = f2b(a[3]);
    r[4] = f2b(b[0]); r[5] = f2b(b[1]); r[6] = f2b(b[2]); r[7] = f2b(b[3]);
    ((u16x8*)xb)[i] = r;
  } else if (blk < 16896) {
    // ---- fold_w ----
    const int b2 = blk - 16384;
    const int kbase = (b2 & 15) * 64, h = (b2 >> 4) & 15, sel = b2 >> 8;
    float (*Wt)[65] = (float(*)[65])smem;            // 64*65*4 = 16640
    float (*P)[64] = (float(*)[64])(smem + 16640);   // 64*64*4 = 16384
    const float* W = sel ? Wk : Wq;
    {
      int row = t >> 2, cb = (t & 3) * 16;
#pragma unroll
      for (int i = 0; i < 4; ++i) {
        f32x4 vv = *(const f32x4*)(W + (size_t)(kbase + row) * 1024 + h * 64 + cb + i * 4);
        Wt[row][cb + i * 4 + 0] = vv[0]; Wt[row][cb + i * 4 + 1] = vv[1];
        Wt[row][cb + i * 4 + 2] = vv[2]; Wt[row][cb + i * 4 + 3] = vv[3];
        f32x4 pp = *(const f32x4*)(proj + (size_t)row * 64 + cb + i * 4);
        P[row][cb + i * 4 + 0] = pp[0]; P[row][cb + i * 4 + 1] = pp[1];
        P[row][cb + i * 4 + 2] = pp[2]; P[row][cb + i * 4 + 3] = pp[3];
      }
    }
    __syncthreads();
    const int kk = t & 63, fg = (t >> 6) * 16;
    float acc[16] = {};
    for (int d = 0; d < 64; ++d) {
      float w = Wt[kk][d];
#pragma unroll
      for (int ff = 0; ff < 16; ++ff) acc[ff] = fmaf(w, P[d][fg + ff], acc[ff]);
    }
#pragma unroll
    for (int ff = 0; ff < 16; ++ff)
      WqkvT[(size_t)(sel * 1024 + h * 64 + fg + ff) * 1024 + kbase + kk] = f2b(acc[ff]);
  } else if (blk < 17408) {
    // ---- transpose_cast (Wv or Wo) ----
    const bool isV = blk < 17152;
    const int b3 = blk - (isV ? 16896 : 17152);
    const float* W = isV ? Wv : Wo;
    u16* Wt_out = isV ? (WqkvT + (size_t)2048 * 1024) : woT;
    float (*tile)[65] = (float(*)[65])smem;
    const int k0 = (b3 & 15) * 64, n0 = (b3 >> 4) * 64;
    const int r = t >> 4, c4 = (t & 15) * 4;
#pragma unroll
    for (int i = 0; i < 4; ++i) {
      f32x4 vv = *(const f32x4*)(W + (size_t)(k0 + r + i * 16) * 1024 + n0 + c4);
      tile[r + i * 16][c4 + 0] = vv[0];
      tile[r + i * 16][c4 + 1] = vv[1];
      tile[r + i * 16][c4 + 2] = vv[2];
      tile[r + i * 16][c4 + 3] = vv[3];
    }
    __syncthreads();
#pragma unroll
    for (int i = 0; i < 4; ++i) {
      int nrow = r + i * 16;
      u16x4 o;
#pragma unroll
      for (int j = 0; j < 4; ++j) o[j] = f2b(tile[c4 + j][nrow]);
      *(u16x4*)(Wt_out + (size_t)(n0 + nrow) * 1024 + k0 + c4) = o;
    }
  } else {
    // ---- zero kvT + ksum (contiguous 0x104000 bytes = 66560 f32x4) ----
    const size_t i = (size_t)(blk - 17408) * 256 + t;
    if (i < 66560) {
      f32x4 z = {0.f, 0.f, 0.f, 0.f};
      ((f32x4*)zbase)[i] = z;
    }
  }
}

// ---------------- 256x256 BK=64 single-barrier-per-tile bf16 MFMA GEMM ----------------
// K-loop identical to round-3 (proven: 1010 TF, no spill, 0 K-loop bank conflicts).
// QKV k/v epilogue: bounce C-tile through the (free) 128KB LDS with an XOR-swizzled
// transpose, then write kT[b,h,f,n] / vT[b,h,d,n] (n-contiguous, coalesced 16B
// stores) for the MFMA kv kernel. q keeps [token][1024] (num_den wants rows).
template <int NB, bool QKV>
__global__ void __launch_bounds__(512) gemm256(const u16* __restrict__ Ax,
                                               const u16* __restrict__ Bt,
                                               u16* __restrict__ qo, u16* __restrict__ ko,
                                               u16* __restrict__ vo,
                                               float* __restrict__ Cf,
                                               const float* __restrict__ bias) {
  extern __shared__ __align__(16) u16 lds[];
  const int tid = threadIdx.x;
  // XCD swizzle: flat&7 = xcd; per XCD 16 m-blocks as 2 chunks of 8; n-major groups.
  const int flat = blockIdx.x;
  const int xcd = flat & 7, slot = flat >> 3;
  const int pos = slot & 7, g = slot >> 3;
  const int nc = g % NB, mc = g / NB;
  const int m0 = (xcd * 16 + mc * 8 + pos) * 256;
  const int n0 = nc * 256;
  const int w = tid >> 6, l = tid & 63, quad = l >> 4, lr = l & 15;
  const int wm = w >> 2, wn = w & 3;
  u16* const A0 = lds;
  u16* const B0 = lds + 16384;
  u16* const A1 = lds + 32768;
  u16* const B1 = lds + 49152;
  const int c0 = ((quad * 16) ^ ((lr & 7) << 4)) >> 1;
  const int c1 = ((64 + quad * 16) ^ ((lr & 7) << 4)) >> 1;
  const int rst = tid >> 3;
  const int ksw8 = ((tid & 7) ^ (rst & 7)) * 8;
  const int tid8 = tid * 8;

  f32x4 acc[8][4] = {};
  bf16x8 af[4][2];
  bf16x8 bl[2][2];
  bf16x8 bh[2][2];

#define STG(SRC, ROW0, KT, DST) do {                                         \
    const u16* s_ = (SRC) + (size_t)((ROW0) + rst) * 1024 + (KT) + ksw8;     \
    g2l16(s_, (DST) + tid8);                                                 \
    g2l16(s_ + 64 * 1024, (DST) + 4096 + tid8);                              \
  } while (0)

#define RD_A(BASE, MH) do {                                                  \
    const u16* ap_ = (BASE) + wm * 8192 + (MH) * 4096;                       \
    _Pragma("unroll")                                                        \
    for (int ii = 0; ii < 4; ++ii) {                                         \
      const int ro_ = (ii * 16 + lr) * 64;                                   \
      af[ii][0] = *(const bf16x8*)(ap_ + ro_ + c0);                          \
      af[ii][1] = *(const bf16x8*)(ap_ + ro_ + c1);                          \
    } } while (0)

#define RD_B(DST2, BASE, J0) do {                                            \
    const u16* bp_ = (BASE) + (wn >> 1) * 8192 + (wn & 1) * 4096;            \
    _Pragma("unroll")                                                        \
    for (int jj = 0; jj < 2; ++jj) {                                         \
      const int ro_ = (((J0) + jj) * 16 + lr) * 64;                          \
      DST2[jj][0] = *(const bf16x8*)(bp_ + ro_ + c0);                        \
      DST2[jj][1] = *(const bf16x8*)(bp_ + ro_ + c1);                        \
    } } while (0)

#define CL(MH, BF2, NH) do {                                                 \
    __builtin_amdgcn_s_setprio(1);                                           \
    _Pragma("unroll")                                                        \
    for (int ii = 0; ii < 4; ++ii)                                           \
      _Pragma("unroll")                                                      \
      for (int jj = 0; jj < 2; ++jj)                                         \
        _Pragma("unroll")                                                    \
        for (int ks = 0; ks < 2; ++ks)                                       \
          acc[(MH) * 4 + ii][(NH) * 2 + jj] =                                \
              __builtin_amdgcn_mfma_f32_16x16x32_bf16(                       \
                  af[ii][ks], BF2[jj][ks],                                   \
                  acc[(MH) * 4 + ii][(NH) * 2 + jj], 0, 0, 0);               \
    __builtin_amdgcn_s_setprio(0);                                           \
  } while (0)

#define SB0() __builtin_amdgcn_sched_barrier(0)
#define WAIT_LGKM(N) do { asm volatile("s_waitcnt lgkmcnt(" #N ")" ::: "memory"); SB0(); } while (0)
#define WAIT_VM0()   do { asm volatile("s_waitcnt vmcnt(0)" ::: "memory"); SB0(); } while (0)
#define BARRIER()    do { asm volatile("s_barrier" ::: "memory"); SB0(); } while (0)

  STG(Ax, m0, 0, A0); STG(Ax, m0 + 128, 0, A0 + 8192);
  STG(Bt, n0, 0, B0); STG(Bt, n0 + 128, 0, B0 + 8192);
  STG(Ax, m0, 64, A1); STG(Ax, m0 + 128, 64, A1 + 8192);
  STG(Bt, n0, 64, B1); STG(Bt, n0 + 128, 64, B1 + 8192);
  asm volatile("s_waitcnt vmcnt(8)" ::: "memory");
  SB0();
  BARRIER();
  RD_B(bl, B0, 0);   // lgkm queue tail order must be [bl(4), af(8), bh(4)]
  RD_A(A0, 0);
  RD_B(bh, B0, 2);
  SB0();

#pragma unroll
  for (int t = 0; t < 16; ++t) {
    u16* const Ac = (t & 1) ? A1 : A0;
    u16* const Bc = (t & 1) ? B1 : B0;
    u16* const An = (t & 1) ? A0 : A1;
    u16* const Bn = (t & 1) ? B0 : B1;
    WAIT_LGKM(4);
    CL(0, bl, 0);
    WAIT_LGKM(0);
    CL(0, bh, 1);
    SB0();
    RD_A(Ac, 1);
    WAIT_LGKM(0);
    CL(1, bl, 0);
    SB0();
    if (t < 15) {
      WAIT_VM0();
      BARRIER();
      if (t < 14) {
        STG(Ax, m0,       (t + 2) * 64, Ac);
        STG(Ax, m0 + 128, (t + 2) * 64, Ac + 8192);
        STG(Bt, n0,       (t + 2) * 64, Bc);
        STG(Bt, n0 + 128, (t + 2) * 64, Bc + 8192);
      }
      RD_B(bl, Bn, 0);
      SB0();
    }
    CL(1, bh, 1);
    SB0();
    if (t < 15) {
      RD_A(An, 0);
      RD_B(bh, Bn, 2);
      SB0();
    }
  }
#undef STG
#undef RD_A
#undef RD_B
#undef CL
#undef WAIT_LGKM
#undef WAIT_VM0
#undef BARRIER

  const int rbase = m0 + wm * 128 + quad * 4;
  if (QKV) {
    const int sel = n0 >> 10;
    if (sel == 0) {
      const int cb = (n0 & 1023) + wn * 64 + lr;
#pragma unroll
      for (int mi = 0; mi < 8; ++mi)
#pragma unroll
        for (int nj = 0; nj < 4; ++nj)
#pragma unroll
          for (int rr = 0; rr < 4; ++rr) {
            int row = rbase + mi * 16 + rr;
            float v = fmaxf(acc[mi][nj][rr], 0.0f) + FLA_EPS;
            qo[(size_t)row * 1024 + cb + nj * 16] = f2b(v);
          }
    } else {
      // k/v: LDS-bounce transpose -> kT/vT[b,h,f,n] (n contiguous)
      const bool isK = (sel == 1);
      __syncthreads();
#pragma unroll
      for (int mi = 0; mi < 8; ++mi)
#pragma unroll
        for (int nj = 0; nj < 4; ++nj) {
          const int r0 = wm * 128 + mi * 16 + quad * 4;
          const int c = wn * 64 + nj * 16 + lr;
          u16x4 pk;
#pragma unroll
          for (int rr = 0; rr < 4; ++rr) {
            float v = acc[mi][nj][rr];
            if (isK) v = fmaxf(v, 0.0f) + FLA_EPS;
            pk[rr] = f2b(v);
          }
          *(u16x4*)&lds[c * 256 + (((r0 >> 3) ^ (c & 7)) << 3) + (r0 & 7)] = pk;
        }
      __syncthreads();
      u16* dstT = isK ? ko : vo;
      const int bI = m0 >> 13, s0 = m0 & 8191;
      const size_t cb0 = ((size_t)bI << 10) + (n0 & 1023);
#pragma unroll
      for (int i = 0; i < 16; ++i) {
        const int c = w * 32 + i * 2 + (l >> 5);
        const int u = (l & 31) ^ (c & 7);
        u16x8 vv = *(const u16x8*)&lds[c * 256 + u * 8];
        *(u16x8*)(dstT + (cb0 + c) * 8192 + s0 + (l & 31) * 8) = vv;
      }
    }
  } else {
#pragma unroll
    for (int mi = 0; mi < 8; ++mi)
#pragma unroll
      for (int nj = 0; nj < 4; ++nj) {
        const int cb = n0 + wn * 64 + nj * 16 + lr;
#pragma unroll
        for (int rr = 0; rr < 4; ++rr) {
          int row = rbase + mi * 16 + rr;
          Cf[(size_t)row * 1024 + cb] = acc[mi][nj][rr] + bias[cb];
        }
      }
  }
}

// ---------------- kv via MFMA, atomic accumulation into kvT/ksum ----------------
// Per (bh, chunk of 1024 n): D[d][f] += sum_n vT[d][n]*kT[f][n]. 8 chunk-blocks per
// bh accumulate via device-scope fp32 atomicAdd (accumulators zeroed by prep).
__global__ void __launch_bounds__(256) kv_mfma(const u16* __restrict__ kT,
                                               const u16* __restrict__ vT,
                                               float* __restrict__ kvT,
                                               float* __restrict__ ksum) {
  __shared__ __align__(16) u16 Av[2][4096];
  __shared__ __align__(16) u16 Bk[2][4096];
  const int tid = threadIdx.x;
  const int bh = blockIdx.x, chunk = blockIdx.y;
  const size_t n0 = (size_t)chunk * 1024;
  const u16* vbp = vT + (size_t)bh * 64 * 8192;
  const u16* kbp = kT + (size_t)bh * 64 * 8192;
  const int w = tid >> 6, l = tid & 63, quad = l >> 4, lr = l & 15;
  const int wd = w >> 1, wf = w & 1;
  const int dstg = tid >> 3, kc = tid & 7;
  const int sc0 = (kc ^ (dstg & 7)) * 8;
  f32x4 acc[2][2] = {};
  float ksm[2] = {0.f, 0.f};

#define KVSTG(BUF, T) do {                                                    \
    const size_t off_ = n0 + (size_t)(T) * 64;                                \
    g2l16(vbp + (size_t)dstg * 8192 + off_ + sc0, &Av[BUF][tid8_]);           \
    g2l16(vbp + (size_t)(dstg + 32) * 8192 + off_ + sc0, &Av[BUF][2048 + tid8_]); \
    g2l16(kbp + (size_t)dstg * 8192 + off_ + sc0, &Bk[BUF][tid8_]);           \
    g2l16(kbp + (size_t)(dstg + 32) * 8192 + off_ + sc0, &Bk[BUF][2048 + tid8_]); \
  } while (0)
  const int tid8_ = tid * 8;

  KVSTG(0, 0);
  for (int t = 0; t < 16; ++t) {
    const int buf = t & 1;
    if (t < 15) {
      KVSTG(buf ^ 1, t + 1);
      asm volatile("s_waitcnt vmcnt(4)" ::: "memory");
    } else {
      asm volatile("s_waitcnt vmcnt(0)" ::: "memory");
    }
    __builtin_amdgcn_sched_barrier(0);
    __builtin_amdgcn_s_barrier();
    bf16x8 av[2][2], bk[2][2];
#pragma unroll
    for (int di = 0; di < 2; ++di)
#pragma unroll
      for (int ks = 0; ks < 2; ++ks) {
        const int d = wd * 32 + di * 16 + lr;
        av[di][ks] = *(const bf16x8*)&Av[buf][d * 64 + ((ks * 4 + quad) ^ (d & 7)) * 8];
        const int f = wf * 32 + di * 16 + lr;
        bk[di][ks] = *(const bf16x8*)&Bk[buf][f * 64 + ((ks * 4 + quad) ^ (f & 7)) * 8];
      }
    asm volatile("s_waitcnt lgkmcnt(0)" ::: "memory");
    __builtin_amdgcn_sched_barrier(0);
#pragma unroll
    for (int di = 0; di < 2; ++di)
#pragma unroll
      for (int fj = 0; fj < 2; ++fj)
#pragma unroll
        for (int ks = 0; ks < 2; ++ks)
          acc[di][fj] = __builtin_amdgcn_mfma_f32_16x16x32_bf16(
              av[di][ks], bk[fj][ks], acc[di][fj], 0, 0, 0);
    if (w < 2) {
#pragma unroll
      for (int fj = 0; fj < 2; ++fj) {
        ksm[fj] += bsum8(bk[fj][0]);
        ksm[fj] += bsum8(bk[fj][1]);
      }
    }
    __builtin_amdgcn_s_barrier();
  }
#undef KVSTG

  float* pb = kvT + (size_t)bh * 4096;
#pragma unroll
  for (int di = 0; di < 2; ++di)
#pragma unroll
    for (int fj = 0; fj < 2; ++fj)
#pragma unroll
      for (int rr = 0; rr < 4; ++rr) {
        const int d = wd * 32 + di * 16 + quad * 4 + rr;
        const int f = wf * 32 + fj * 16 + lr;
        atomicAdd(&pb[d * 64 + f], acc[di][fj][rr]);
      }
  if (w < 2) {
#pragma unroll
    for (int fj = 0; fj < 2; ++fj) {
      float s = ksm[fj];
      s += __shfl_xor(s, 16, 64);
      s += __shfl_xor(s, 32, 64);
      if (l < 16)
        atomicAdd(&ksum[(size_t)bh * 64 + wf * 32 + fj * 16 + l], s);
    }
  }
}

// ---------------- num/den + normalize ----------------
__global__ void __launch_bounds__(256) num_den(const u16* __restrict__ qf,
                                               const float* __restrict__ kvT,
                                               const float* __restrict__ ksum,
                                               u16* __restrict__ outI) {
  __shared__ __align__(16) u16 As[128 * 64];
  __shared__ __align__(16) u16 Bs[64 * 64];
  __shared__ float ksum_s[64];
  __shared__ float den_s[128];
  const int t = threadIdx.x;
  const size_t tok0 = (size_t)blockIdx.x * 128;
  const int h = blockIdx.y;
  const int bh = (blockIdx.x >> 6) * 16 + h;
  const int w = t >> 6, l = t & 63, quad = l >> 4, lr = l & 15;
  const int trow = t >> 3, tcol = (t & 7) * 8;
#pragma unroll
  for (int i = 0; i < 4; ++i) {
    int r = i * 32 + trow;
    g2l16(qf + (tok0 + r) * 1024 + h * 64 + tcol, &As[r * 64 + tcol]);
  }
  {
    const float* kvb = kvT + (size_t)bh * 4096;
    int d = t >> 2, cb = (t & 3) * 16;
    u16x8 o0, o1;
#pragma unroll
    for (int q4 = 0; q4 < 2; ++q4) {
      f32x4 vv = *(const f32x4*)(kvb + d * 64 + cb + q4 * 4);
      o0[q4 * 4 + 0] = f2b(vv[0]); o0[q4 * 4 + 1] = f2b(vv[1]);
      o0[q4 * 4 + 2] = f2b(vv[2]); o0[q4 * 4 + 3] = f2b(vv[3]);
    }
#pragma unroll
    for (int q4 = 0; q4 < 2; ++q4) {
      f32x4 vv = *(const f32x4*)(kvb + d * 64 + cb + 8 + q4 * 4);
      o1[q4 * 4 + 0] = f2b(vv[0]); o1[q4 * 4 + 1] = f2b(vv[1]);
      o1[q4 * 4 + 2] = f2b(vv[2]); o1[q4 * 4 + 3] = f2b(vv[3]);
    }
    *(u16x8*)&Bs[d * 64 + cb] = o0;
    *(u16x8*)&Bs[d * 64 + cb + 8] = o1;
  }
  if (t < 64) ksum_s[t] = ksum[(size_t)bh * 64 + t];
  __syncthreads();
  if (t < 128) {
    float d = FLA_EPS;
#pragma unroll
    for (int jj = 0; jj < 64; ++jj) {
      int f = (t + jj) & 63;
      d += b2f(As[t * 64 + f]) * ksum_s[f];
    }
    den_s[t] = d;
  }
  __syncthreads();
  f32x4 acc[2][4] = {};
  const int wrow = w * 32;
#pragma unroll
  for (int ks = 0; ks < 2; ++ks) {
    bf16x8 af[2], bfr[4];
#pragma unroll
    for (int i = 0; i < 2; ++i)
      af[i] = *(const bf16x8*)&As[(wrow + i * 16 + lr) * 64 + ks * 32 + quad * 8];
#pragma unroll
    for (int j = 0; j < 4; ++j)
      bfr[j] = *(const bf16x8*)&Bs[(j * 16 + lr) * 64 + ks * 32 + quad * 8];
#pragma unroll
    for (int i = 0; i < 2; ++i)
#pragma unroll
      for (int j = 0; j < 4; ++j)
        acc[i][j] = __builtin_amdgcn_mfma_f32_16x16x32_bf16(af[i], bfr[j], acc[i][j], 0, 0, 0);
  }
#pragma unroll
  for (int i = 0; i < 2; ++i)
#pragma unroll
    for (int j = 0; j < 4; ++j)
#pragma unroll
      for (int rr = 0; rr < 4; ++rr) {
        int rloc = wrow + i * 16 + quad * 4 + rr;
        float v = acc[i][j][rr] / den_s[rloc];
        outI[(tok0 + rloc) * 1024 + h * 64 + j * 16 + lr] = f2b(v);
      }
}

extern "C" void kernel_launch(void* const* d_in, const int* in_sizes, int n_in,
                              void* d_out, int out_size, void* d_ws, size_t ws_size,
                              hipStream_t stream) {
  const float* x    = (const float*)d_in[0];
  const float* Wq   = (const float*)d_in[1];
  const float* Wk   = (const float*)d_in[2];
  const float* Wv   = (const float*)d_in[3];
  const float* proj = (const float*)d_in[4];
  const float* Wo   = (const float*)d_in[5];
  const float* bo   = (const float*)d_in[6];
  float* out = (float*)d_out;

  char* ws = (char*)d_ws;
  const size_t SZ = 1ull << 26;
  u16* xb     = (u16*)(ws + 0);
  u16* qb     = (u16*)(ws + SZ);
  u16* kb     = (u16*)(ws + 2 * SZ);   // kT[b,h,f,n]
  u16* vb     = (u16*)(ws + 3 * SZ);   // vT[b,h,d,n]
  u16* WqkvT  = (u16*)(ws + 4 * SZ);
  u16* woT    = (u16*)(ws + 4 * SZ + 0x600000);
  float* kvT    = (float*)(ws + 4 * SZ + 0x800000);             // 1 MB
  float* ksum   = (float*)(ws + 4 * SZ + 0x800000 + 0x100000);  // 16 KB (contiguous)

  static int attr_done = 0;
  if (!attr_done) {
    (void)hipFuncSetAttribute((const void*)gemm256<12, true>,
                              hipFuncAttributeMaxDynamicSharedMemorySize, 131072);
    (void)hipFuncSetAttribute((const void*)gemm256<4, false>,
                              hipFuncAttributeMaxDynamicSharedMemorySize, 131072);
    attr_done = 1;
  }

  prep<<<17668, 256, 0, stream>>>(x, Wq, Wk, Wv, Wo, proj, xb, WqkvT, woT, kvT);
  gemm256<12, true><<<1536, 512, 131072, stream>>>(xb, WqkvT, qb, kb, vb, nullptr, nullptr);
  kv_mfma<<<dim3(64, 8), 256, 0, stream>>>(kb, vb, kvT, ksum);
  num_den<<<dim3(256, 16), 256, 0, stream>>>(qb, kvT, ksum, xb);
  gemm256<4, false><<<512, 512, 131072, stream>>>(xb, woT, nullptr, nullptr, nullptr, out, bo);
}